// Round 6
// baseline (170.435 us; speedup 1.0000x reference)
//
#include <hip/hip_runtime.h>
#include <hip/hip_fp16.h>

typedef _Float16 f16;
using f16x8 = __attribute__((ext_vector_type(8))) _Float16;
using h2 = __attribute__((ext_vector_type(2))) __fp16;   // cvt_pkrtz return type
using f32x4 = __attribute__((ext_vector_type(4))) float;
using f32x16 = __attribute__((ext_vector_type(16))) float;

#define LOG2E 1.4426950408889634f

__device__ __forceinline__ void gload16(const void* g, void* l) {
  __builtin_amdgcn_global_load_lds(
      (const __attribute__((address_space(1))) void*)g,
      (__attribute__((address_space(3))) void*)l, 16, 0, 0);
}

__device__ __forceinline__ float b32(h2 x) { return __builtin_bit_cast(float, x); }
__device__ __forceinline__ unsigned u32(h2 x) { return __builtin_bit_cast(unsigned, x); }

// ---------------- convert f32 -> fp16 ----------------
// ws layout (halves): [queryh 4M][keyh 4M][valueh 4M][wqh 1M][wkh 1M][wvh 1M][woh 1M]
__global__ __launch_bounds__(256) void convert_k(
    const float* __restrict__ q, const float* __restrict__ k, const float* __restrict__ v,
    const float* __restrict__ wq, const float* __restrict__ wk,
    const float* __restrict__ wv, const float* __restrict__ wo,
    f16* __restrict__ dst) {
  const size_t SEG = (size_t)4 * 1024 * 1024;
  size_t i = ((size_t)blockIdx.x * 256 + threadIdx.x) * 8;
  const float* src; size_t off;
  if (i < SEG)            { src = q;  off = i; }
  else if (i < 2 * SEG)   { src = k;  off = i - SEG; }
  else if (i < 3 * SEG)   { src = v;  off = i - 2 * SEG; }
  else {
    size_t wi = i - 3 * SEG;
    int s = (int)(wi >> 20);
    src = (s == 0) ? wq : (s == 1) ? wk : (s == 2) ? wv : wo;
    off = wi & ((1u << 20) - 1);
  }
  float4 a = *(const float4*)(src + off);
  float4 b = *(const float4*)(src + off + 4);
  f16x8 o;
  o[0] = (f16)a.x; o[1] = (f16)a.y; o[2] = (f16)a.z; o[3] = (f16)a.w;
  o[4] = (f16)b.x; o[5] = (f16)b.y; o[6] = (f16)b.z; o[7] = (f16)b.w;
  *(f16x8*)(dst + i) = o;
}

// ---------------- GEMM: C = A @ W^T (+bias), 128x128 tile, BK=32, 2-phase dbuf ----------------
template <int QKV>
__global__ __launch_bounds__(256) void gemm_k(
    const f16* __restrict__ Abase, const f16* __restrict__ Wbase,
    const float* __restrict__ b0, const float* __restrict__ b1, const float* __restrict__ b2,
    const float* __restrict__ cosT, const float* __restrict__ sinT,
    f16* __restrict__ qh, f16* __restrict__ kh, f16* __restrict__ vt,
    float* __restrict__ outF) {
  __shared__ f16 As[2][128 * 32];
  __shared__ f16 Bs[2][128 * 32];
  int tid = threadIdx.x, wid = tid >> 6, lane = tid & 63;
  int z = QKV ? blockIdx.z : 0;
  const f16* A = Abase + (size_t)z * (4u * 1024 * 1024);
  const f16* W = Wbase + (size_t)z * (1024u * 1024);
  int m0 = blockIdx.y * 128, n0 = blockIdx.x * 128;
  int wr = wid >> 1, wc = wid & 1;
  f32x4 acc[4][4] = {};

  // staging addresses (kt-invariant): thread stages 16B of row p*64+(tid>>2), slot XOR-swizzled
  int srow = tid >> 2;
  int sslot = (tid & 3) ^ (srow & 3);
  const f16* asrc0 = A + (size_t)(m0 + srow) * 1024 + sslot * 8;
  const f16* asrc1 = A + (size_t)(m0 + 64 + srow) * 1024 + sslot * 8;
  const f16* bsrc0 = W + (size_t)(n0 + srow) * 1024 + sslot * 8;
  const f16* bsrc1 = W + (size_t)(n0 + 64 + srow) * 1024 + sslot * 8;

  // frag read offsets (halves, kt-invariant)
  int aoff[4], boff[4];
#pragma unroll
  for (int i = 0; i < 4; ++i) {
    int row = wr * 64 + i * 16 + (lane & 15);
    aoff[i] = row * 32 + (((lane >> 4) ^ (row & 3)) * 8);
    int col = wc * 64 + i * 16 + (lane & 15);
    boff[i] = col * 32 + (((lane >> 4) ^ (col & 3)) * 8);
  }

  // prologue: stage K-step 0 into buf 0
  gload16(asrc0, (void*)(&As[0][0] + wid * 512));
  gload16(asrc1, (void*)(&As[0][0] + 2048 + wid * 512));
  gload16(bsrc0, (void*)(&Bs[0][0] + wid * 512));
  gload16(bsrc1, (void*)(&Bs[0][0] + 2048 + wid * 512));
  __syncthreads();

  int cur = 0;
  for (int kt = 0; kt < 32; ++kt) {
    if (kt + 1 < 32) {  // issue next K-step loads before compute (2-phase)
      int k0 = (kt + 1) * 32;
      gload16(asrc0 + k0, (void*)(&As[cur ^ 1][0] + wid * 512));
      gload16(asrc1 + k0, (void*)(&As[cur ^ 1][0] + 2048 + wid * 512));
      gload16(bsrc0 + k0, (void*)(&Bs[cur ^ 1][0] + wid * 512));
      gload16(bsrc1 + k0, (void*)(&Bs[cur ^ 1][0] + 2048 + wid * 512));
    }
    f16x8 af[4], bf[4];
#pragma unroll
    for (int i = 0; i < 4; ++i) {
      af[i] = *(const f16x8*)(&As[cur][0] + aoff[i]);
      bf[i] = *(const f16x8*)(&Bs[cur][0] + boff[i]);
    }
#pragma unroll
    for (int i = 0; i < 4; ++i)
#pragma unroll
      for (int j = 0; j < 4; ++j)
        acc[i][j] = __builtin_amdgcn_mfma_f32_16x16x32_f16(af[i], bf[j], acc[i][j], 0, 0, 0);
    __syncthreads();
    cur ^= 1;
  }

  const float* bias = QKV ? (z == 0 ? b0 : (z == 1 ? b1 : b2)) : b0;
#pragma unroll
  for (int i = 0; i < 4; ++i) {
#pragma unroll
    for (int j = 0; j < 4; ++j) {
#pragma unroll
      for (int r = 0; r < 4; ++r) {
        int grow = m0 + wr * 64 + i * 16 + ((lane >> 4) << 2) + r;
        int gcol = n0 + wc * 64 + j * 16 + (lane & 15);
        float val = acc[i][j][r] + bias[gcol];
        if (QKV) {
          int s = grow & 2047, bb = grow >> 11;
          int h = gcol >> 6, dk = gcol & 63;
          if (z < 2) {
            float pr = __shfl_xor(val, 1);
            int j2 = gcol >> 1;
            float c = cosT[s * 512 + j2], sn = sinT[s * 512 + j2];
            val = (lane & 1) ? (c * val + sn * pr) : (c * val - sn * pr);
            if (z == 0) val *= 0.125f * LOG2E;  // fold 1/sqrt(DK) and log2(e) into Q
            f16* dst = (z == 0) ? qh : kh;
            dst[(((size_t)bb * 16 + h) * 2048 + s) * 64 + dk] = (f16)val;
          } else {
            vt[(((size_t)bb * 16 + h) * 64 + dk) * 2048 + s] = (f16)val;  // V transposed
          }
        } else {
          outF[(size_t)grow * 1024 + gcol] = val;
        }
      }
    }
  }
}

// ---------------- flash attention: 32x32 swapped, LDS-staged, split-K x2 ----------------
// Block = 4 waves (256 thr); wave owns 32 q-rows (lane&31 = qrow); block covers 128 rows.
// All 4 waves share one double-buffered K/V LDS tile (gload_lds, XOR-swizzled).
// S^T = mfma_32x32x16(K, Q); out^T = mfma(V^T, P^T). Each block does 1024 keys (ks half).
// Writes normalized partial O (fp16) + (m,l) per row; combine_k merges the two halves.
__global__ __launch_bounds__(256, 4) void flash_k(
    const f16* __restrict__ qh, const f16* __restrict__ kh, const f16* __restrict__ vt,
    f16* __restrict__ op, float2* __restrict__ mlbuf) {
  __shared__ f16 Ks[2][64 * 64];
  __shared__ f16 Vs[2][64 * 64];   // Vs[dk][key]
  int tid = threadIdx.x, wid = tid >> 6, lane = tid & 63;
  int l31 = lane & 31, hi = lane >> 5;
  int qt = blockIdx.x, h = blockIdx.y, z = blockIdx.z;  // z = b*2 + ks
  int b = z >> 1, ks = z & 1;
  size_t bh = (size_t)b * 16 + h;
  const f16* qp = qh + bh * (2048 * 64);
  const f16* kp = kh + bh * (2048 * 64) + (size_t)ks * 1024 * 64;
  const f16* vp = vt + bh * (64 * 2048) + ks * 1024;
  int qrow = qt * 128 + wid * 32 + l31;

  // Q fragments: qf[kk][e] = Q[qrow][kk*16 + hi*8 + e]
  f16x8 qf[4];
#pragma unroll
  for (int kk = 0; kk < 4; ++kk)
    qf[kk] = *(const f16x8*)(qp + (size_t)qrow * 64 + kk * 16 + hi * 8);

  // staging: tile = 64 rows x 128B = 512 16B-slots; 2 issues per array per thread.
  // physical slot (row, c) holds logical chunk c ^ (row&7)
  int srowA = tid >> 3, srowB = srowA + 32;
  int schA = (tid & 7) ^ (srowA & 7);
  int schB = (tid & 7) ^ (srowB & 7);
  const f16* ksrcA = kp + (size_t)srowA * 64 + schA * 8;    // + kt*4096
  const f16* ksrcB = kp + (size_t)srowB * 64 + schB * 8;
  const f16* vsrcA = vp + (size_t)srowA * 2048 + schA * 8;  // + kt*64
  const f16* vsrcB = vp + (size_t)srowB * 2048 + schB * 8;

  // swizzled read byte-offsets (same formula serves K rows=key and V rows=dk)
  int offr[2][4];
#pragma unroll
  for (int kb = 0; kb < 2; ++kb)
#pragma unroll
    for (int kk = 0; kk < 4; ++kk) {
      int row = kb * 32 + l31;
      offr[kb][kk] = (row * 128 + kk * 32 + hi * 16) ^ ((row & 7) << 4);
    }

  float m_ = -1e30f, l_ = 0.f;
  f32x16 oacc[2] = {};

  // prologue: stage tile 0 into buf 0
  gload16(ksrcA, (char*)&Ks[0][0] + tid * 16);
  gload16(ksrcB, (char*)&Ks[0][0] + 4096 + tid * 16);
  gload16(vsrcA, (char*)&Vs[0][0] + tid * 16);
  gload16(vsrcB, (char*)&Vs[0][0] + 4096 + tid * 16);
  __syncthreads();

  int cur = 0;
  for (int kt = 0; kt < 16; ++kt) {
    if (kt + 1 < 16) {  // issue next-tile loads before compute
      gload16(ksrcA + (size_t)(kt + 1) * 4096, (char*)&Ks[cur ^ 1][0] + tid * 16);
      gload16(ksrcB + (size_t)(kt + 1) * 4096, (char*)&Ks[cur ^ 1][0] + 4096 + tid * 16);
      gload16(vsrcA + (size_t)(kt + 1) * 64, (char*)&Vs[cur ^ 1][0] + tid * 16);
      gload16(vsrcB + (size_t)(kt + 1) * 64, (char*)&Vs[cur ^ 1][0] + 4096 + tid * 16);
    }

    // QK^T (S^T: lane owns one q-row, 32 scores across regs + cross-half)
    const char* kbase = (const char*)&Ks[cur][0];
    f32x16 sacc[2] = {};
#pragma unroll
    for (int kb = 0; kb < 2; ++kb)
#pragma unroll
      for (int kk = 0; kk < 4; ++kk) {
        f16x8 af = *(const f16x8*)(kbase + offr[kb][kk]);
        sacc[kb] = __builtin_amdgcn_mfma_f32_32x32x16_f16(af, qf[kk], sacc[kb], 0, 0, 0);
      }

    // tree max over 32 local scores, then cross-half
    float t16[16];
#pragma unroll
    for (int i = 0; i < 16; ++i) t16[i] = fmaxf(sacc[0][i], sacc[1][i]);
#pragma unroll
    for (int s = 8; s; s >>= 1)
#pragma unroll
      for (int i = 0; i < s; ++i) t16[i] = fmaxf(t16[i], t16[i + s]);
    float pmax = fmaxf(t16[0], __shfl_xor(t16[0], 32));

    // defer-max (T13, THR=8): wave-uniform rescale skip
    if (!__all(pmax <= m_ + 8.0f)) {
      float mn = fmaxf(m_, pmax);
      float al = __builtin_amdgcn_exp2f(m_ - mn);
      m_ = mn;
      l_ *= al;
#pragma unroll
      for (int mb = 0; mb < 2; ++mb)
#pragma unroll
        for (int i = 0; i < 16; ++i) oacc[mb][i] *= al;
    }

    // P = 2^(s - m), tree sum
#pragma unroll
    for (int kb = 0; kb < 2; ++kb)
#pragma unroll
      for (int i = 0; i < 16; ++i)
        sacc[kb][i] = __builtin_amdgcn_exp2f(sacc[kb][i] - m_);
#pragma unroll
    for (int i = 0; i < 16; ++i) t16[i] = sacc[0][i] + sacc[1][i];
#pragma unroll
    for (int s = 8; s; s >>= 1)
#pragma unroll
      for (int i = 0; i < s; ++i) t16[i] += t16[i + s];
    l_ += t16[0] + __shfl_xor(t16[0], 32);

    // pack P^T fragments: pa[kk] slot (hi,e) = key 16kk + 8hi + e (fp16)
    f16x8 pa[4];
#pragma unroll
    for (int kk = 0; kk < 4; ++kk) {
      int kb = kk >> 1, c8 = (kk & 1) * 8;
      float wA = b32(__builtin_amdgcn_cvt_pkrtz(sacc[kb][c8 + 0], sacc[kb][c8 + 1]));
      float wB = b32(__builtin_amdgcn_cvt_pkrtz(sacc[kb][c8 + 2], sacc[kb][c8 + 3]));
      float wC = b32(__builtin_amdgcn_cvt_pkrtz(sacc[kb][c8 + 4], sacc[kb][c8 + 5]));
      float wD = b32(__builtin_amdgcn_cvt_pkrtz(sacc[kb][c8 + 6], sacc[kb][c8 + 7]));
      float oA = __shfl_xor(wA, 32), oB = __shfl_xor(wB, 32);
      float oC = __shfl_xor(wC, 32), oD = __shfl_xor(wD, 32);
      float4 ff;
      ff.x = hi ? oC : wA;
      ff.y = hi ? oD : wB;
      ff.z = hi ? wC : oA;
      ff.w = hi ? wD : oB;
      pa[kk] = __builtin_bit_cast(f16x8, ff);
    }

    // PV: out^T += V^T x P^T
    const char* vbase = (const char*)&Vs[cur][0];
#pragma unroll
    for (int kk = 0; kk < 4; ++kk)
#pragma unroll
      for (int mb = 0; mb < 2; ++mb) {
        f16x8 av = *(const f16x8*)(vbase + offr[mb][kk]);
        oacc[mb] = __builtin_amdgcn_mfma_f32_32x32x16_f16(av, pa[kk], oacc[mb], 0, 0, 0);
      }

    __syncthreads();
    cur ^= 1;
  }

  // epilogue: normalized partial O + (m,l)
  float inv = 1.f / l_;
  f16* orow = op + (((size_t)z * 16 + h) * 2048 + qrow) * 64;
#pragma unroll
  for (int mb = 0; mb < 2; ++mb)
#pragma unroll
    for (int g = 0; g < 4; ++g) {
      uint2 st;
      st.x = u32(__builtin_amdgcn_cvt_pkrtz(oacc[mb][4 * g + 0] * inv, oacc[mb][4 * g + 1] * inv));
      st.y = u32(__builtin_amdgcn_cvt_pkrtz(oacc[mb][4 * g + 2] * inv, oacc[mb][4 * g + 3] * inv));
      *(uint2*)(orow + mb * 32 + g * 8 + hi * 4) = st;
    }
  if (hi == 0)
    mlbuf[((size_t)z * 16 + h) * 2048 + qrow] = make_float2(m_, l_);
}

// ---------------- combine the two split-K halves ----------------
__global__ __launch_bounds__(256) void combine_k(
    const f16* __restrict__ op, const float2* __restrict__ ml, f16* __restrict__ attnout) {
  int t = blockIdx.x * 256 + threadIdx.x;
  int row = t >> 3, c8 = t & 7;
  int b = row >> 15, h = (row >> 11) & 15, qrow = row & 2047;
  size_t i0 = ((size_t)(b * 2 + 0) * 16 + h) * 2048 + qrow;
  size_t i1 = ((size_t)(b * 2 + 1) * 16 + h) * 2048 + qrow;
  float2 a = ml[i0], c = ml[i1];
  float M = fmaxf(a.x, c.x);
  float w1 = a.y * __builtin_amdgcn_exp2f(a.x - M);
  float w2 = c.y * __builtin_amdgcn_exp2f(c.x - M);
  float inv = 1.f / (w1 + w2);
  w1 *= inv; w2 *= inv;
  f16x8 o1 = *(const f16x8*)(op + i0 * 64 + c8 * 8);
  f16x8 o2 = *(const f16x8*)(op + i1 * 64 + c8 * 8);
  f16x8 o;
#pragma unroll
  for (int e = 0; e < 8; ++e)
    o[e] = (f16)(w1 * (float)o1[e] + w2 * (float)o2[e]);
  *(f16x8*)(attnout + ((size_t)b * 2048 + qrow) * 1024 + h * 64 + c8 * 8) = o;
}

extern "C" void kernel_launch(void* const* d_in, const int* in_sizes, int n_in,
                              void* d_out, int out_size, void* d_ws, size_t ws_size,
                              hipStream_t stream) {
  (void)in_sizes; (void)n_in; (void)out_size; (void)ws_size;
  const float* query = (const float*)d_in[0];
  const float* key   = (const float*)d_in[1];
  const float* value = (const float*)d_in[2];
  const float* wq = (const float*)d_in[3];
  const float* bq = (const float*)d_in[4];
  const float* wk = (const float*)d_in[5];
  const float* bk = (const float*)d_in[6];
  const float* wv = (const float*)d_in[7];
  const float* bv = (const float*)d_in[8];
  const float* wo = (const float*)d_in[9];
  const float* bo = (const float*)d_in[10];
  const float* cosT = (const float*)d_in[11];
  const float* sinT = (const float*)d_in[12];
  float* out = (float*)d_out;
  f16* ws = (f16*)d_ws;
  const size_t SEG = (size_t)4 * 1024 * 1024;
  f16* Xh = ws;                       // 3*SEG halves (query/key/value fp16)
  f16* Wh = ws + 3 * SEG;             // 4*1M halves (wq,wk,wv,wo fp16)
  f16* qh = ws + 16u * 1024 * 1024;   // SEG
  f16* kh = qh + SEG;                 // SEG
  f16* vt = kh + SEG;                 // SEG (total 56 MB)
  f16* attnout = ws;                  // aliases queryh (dead after projections)
  f16* op = ws + SEG;                 // aliases keyh+valueh (dead): 8M halves
  float2* mlb = (float2*)(ws + 12u * 1024 * 1024);  // aliases wqh (dead): 1MB

  convert_k<<<8192, 256, 0, stream>>>(query, key, value, wq, wk, wv, wo, ws);
  gemm_k<1><<<dim3(8, 32, 3), 256, 0, stream>>>(Xh, Wh, bq, bk, bv, cosT, sinT,
                                                qh, kh, vt, nullptr);
  flash_k<<<dim3(16, 16, 4), 256, 0, stream>>>(qh, kh, vt, op, mlb);
  combine_k<<<2048, 256, 0, stream>>>(op, mlb, attnout);
  gemm_k<0><<<dim3(8, 32, 1), 256, 0, stream>>>(attnout, Wh + 3u * 1024 * 1024, bo,
                                                nullptr, nullptr, nullptr, nullptr,
                                                nullptr, nullptr, nullptr, out);
}

// Round 8
// 158.017 us; speedup vs baseline: 1.0786x; 1.0786x over previous
//
#include <hip/hip_runtime.h>
#include <hip/hip_fp16.h>

typedef _Float16 f16;
using f16x8 = __attribute__((ext_vector_type(8))) _Float16;
using h2 = __attribute__((ext_vector_type(2))) __fp16;   // cvt_pkrtz return type
using f32x4 = __attribute__((ext_vector_type(4))) float;
using f32x16 = __attribute__((ext_vector_type(16))) float;

#define LOG2E 1.4426950408889634f

__device__ __forceinline__ void gload16(const void* g, void* l) {
  __builtin_amdgcn_global_load_lds(
      (const __attribute__((address_space(1))) void*)g,
      (__attribute__((address_space(3))) void*)l, 16, 0, 0);
}

__device__ __forceinline__ float b32(h2 x) { return __builtin_bit_cast(float, x); }
__device__ __forceinline__ unsigned u32(h2 x) { return __builtin_bit_cast(unsigned, x); }

// ---------------- convert f32 -> fp16 ----------------
// ws layout (halves): [queryh 4M][keyh 4M][valueh 4M][wqh 1M][wkh 1M][wvh 1M][woh 1M]
__global__ __launch_bounds__(256) void convert_k(
    const float* __restrict__ q, const float* __restrict__ k, const float* __restrict__ v,
    const float* __restrict__ wq, const float* __restrict__ wk,
    const float* __restrict__ wv, const float* __restrict__ wo,
    f16* __restrict__ dst) {
  const size_t SEG = (size_t)4 * 1024 * 1024;
  size_t i = ((size_t)blockIdx.x * 256 + threadIdx.x) * 8;
  const float* src; size_t off;
  if (i < SEG)            { src = q;  off = i; }
  else if (i < 2 * SEG)   { src = k;  off = i - SEG; }
  else if (i < 3 * SEG)   { src = v;  off = i - 2 * SEG; }
  else {
    size_t wi = i - 3 * SEG;
    int s = (int)(wi >> 20);
    src = (s == 0) ? wq : (s == 1) ? wk : (s == 2) ? wv : wo;
    off = wi & ((1u << 20) - 1);
  }
  float4 a = *(const float4*)(src + off);
  float4 b = *(const float4*)(src + off + 4);
  f16x8 o;
  o[0] = (f16)a.x; o[1] = (f16)a.y; o[2] = (f16)a.z; o[3] = (f16)a.w;
  o[4] = (f16)b.x; o[5] = (f16)b.y; o[6] = (f16)b.z; o[7] = (f16)b.w;
  *(f16x8*)(dst + i) = o;
}

// ---------------- GEMM: C = A @ W^T (+bias), 128x128 tile, BK=32, 2-phase dbuf ----------------
// XCD-swizzled block mapping; LDS-staged wide-store epilogue for QKV path.
template <int QKV>
__global__ __launch_bounds__(256) void gemm_k(
    const f16* __restrict__ Abase, const f16* __restrict__ Wbase,
    const float* __restrict__ b0, const float* __restrict__ b1, const float* __restrict__ b2,
    const float* __restrict__ cosT, const float* __restrict__ sinT,
    f16* __restrict__ qh, f16* __restrict__ kh, f16* __restrict__ vt,
    float* __restrict__ outF) {
  __shared__ f16 sm[4][128 * 32];   // As = sm[0..1], Bs = sm[2..3]; epilogue reuses all 32KB
  int tid = threadIdx.x, wid = tid >> 6, lane = tid & 63;
  int z = QKV ? blockIdx.z : 0;
  const f16* A = Abase + (size_t)z * (4u * 1024 * 1024);
  const f16* W = Wbase + (size_t)z * (1024u * 1024);

  // T1: XCD-aware swizzle. 256 blocks/z, 8 XCDs; each XCD gets 4 m-panels x all 8 n-blocks.
  int lid = blockIdx.x + (blockIdx.y << 3);
  int xcd = lid & 7, q = lid >> 3;
  int m0 = (xcd * 4 + (q & 3)) * 128;
  int n0 = (q >> 2) * 128;
  int wr = wid >> 1, wc = wid & 1;
  f32x4 acc[4][4] = {};

  // staging addresses (kt-invariant): thread stages 16B of row (tid>>2), slot XOR-swizzled
  int srow = tid >> 2;
  int sslot = (tid & 3) ^ (srow & 3);
  const f16* asrc0 = A + (size_t)(m0 + srow) * 1024 + sslot * 8;
  const f16* asrc1 = A + (size_t)(m0 + 64 + srow) * 1024 + sslot * 8;
  const f16* bsrc0 = W + (size_t)(n0 + srow) * 1024 + sslot * 8;
  const f16* bsrc1 = W + (size_t)(n0 + 64 + srow) * 1024 + sslot * 8;

  // frag read offsets (halves, kt-invariant)
  int aoff[4], boff[4];
#pragma unroll
  for (int i = 0; i < 4; ++i) {
    int row = wr * 64 + i * 16 + (lane & 15);
    aoff[i] = row * 32 + (((lane >> 4) ^ (row & 3)) * 8);
    int col = wc * 64 + i * 16 + (lane & 15);
    boff[i] = col * 32 + (((lane >> 4) ^ (col & 3)) * 8);
  }

  // prologue: stage K-step 0 into buf 0
  gload16(asrc0, (void*)(&sm[0][0] + wid * 512));
  gload16(asrc1, (void*)(&sm[0][0] + 2048 + wid * 512));
  gload16(bsrc0, (void*)(&sm[2][0] + wid * 512));
  gload16(bsrc1, (void*)(&sm[2][0] + 2048 + wid * 512));
  __syncthreads();

  int cur = 0;
  for (int kt = 0; kt < 32; ++kt) {
    if (kt + 1 < 32) {  // issue next K-step loads before compute (2-phase)
      int k0 = (kt + 1) * 32;
      gload16(asrc0 + k0, (void*)(&sm[cur ^ 1][0] + wid * 512));
      gload16(asrc1 + k0, (void*)(&sm[cur ^ 1][0] + 2048 + wid * 512));
      gload16(bsrc0 + k0, (void*)(&sm[2 + (cur ^ 1)][0] + wid * 512));
      gload16(bsrc1 + k0, (void*)(&sm[2 + (cur ^ 1)][0] + 2048 + wid * 512));
    }
    f16x8 af[4], bf[4];
#pragma unroll
    for (int i = 0; i < 4; ++i) {
      af[i] = *(const f16x8*)(&sm[cur][0] + aoff[i]);
      bf[i] = *(const f16x8*)(&sm[2 + cur][0] + boff[i]);
    }
#pragma unroll
    for (int i = 0; i < 4; ++i)
#pragma unroll
      for (int j = 0; j < 4; ++j)
        acc[i][j] = __builtin_amdgcn_mfma_f32_16x16x32_f16(af[i], bf[j], acc[i][j], 0, 0, 0);
    __syncthreads();
    cur ^= 1;
  }

  const float* bias = QKV ? (z == 0 ? b0 : (z == 1 ? b1 : b2)) : b0;

  if (QKV) {
    // ---- phase 1: compute bias/RoPE, stage f16 tile into LDS (chunk-XOR swizzled) ----
    f16* Ct = &sm[0][0];  // [128][128] f16 = 32KB
#pragma unroll
    for (int i = 0; i < 4; ++i) {
#pragma unroll
      for (int j = 0; j < 4; ++j) {
#pragma unroll
        for (int r = 0; r < 4; ++r) {
          int row_l = wr * 64 + i * 16 + ((lane >> 4) << 2) + r;
          int col_l = wc * 64 + j * 16 + (lane & 15);
          int gcol = n0 + col_l;
          float val = acc[i][j][r] + bias[gcol];
          if (z < 2) {
            int s = (m0 + row_l) & 2047;
            float pr = __shfl_xor(val, 1);
            int j2 = gcol >> 1;
            float c = cosT[s * 512 + j2], sn = sinT[s * 512 + j2];
            val = (lane & 1) ? (c * val + sn * pr) : (c * val - sn * pr);
            if (z == 0) val *= 0.125f * LOG2E;  // fold 1/sqrt(DK) and log2(e) into Q
          }
          Ct[row_l * 128 + (col_l ^ ((row_l & 7) << 3))] = (f16)val;
        }
      }
    }
    __syncthreads();
    // ---- phase 2: wide coalesced stores ----
    int bb = m0 >> 11, sbase = m0 & 2047;
    if (z < 2) {
      // qh/kh [bh][s][dk]: thread owns one half-row (64 dk of one head)
      int row = tid >> 1, halfsel = tid & 1;
      int h = (n0 >> 6) + halfsel;
      f16* dst = (z == 0 ? qh : kh) +
                 (((size_t)bb * 16 + h) * 2048 + sbase + row) * 64;
#pragma unroll
      for (int ch = 0; ch < 8; ++ch) {
        int c = halfsel * 64 + ch * 8;
        f16x8 v = *(const f16x8*)(Ct + row * 128 + (c ^ ((row & 7) << 3)));
        *(f16x8*)(dst + ch * 8) = v;
      }
    } else {
      // vt [bh][dk][s]: thread owns one column (dk) x 64 rows (s); 8 x 16B contiguous stores
      int c = tid & 127, halfsel = tid >> 7;
      int h = (n0 >> 6) + (c >> 6), dk = c & 63;
      f16* dst = vt + (((size_t)bb * 16 + h) * 64 + dk) * 2048 + sbase + halfsel * 64;
#pragma unroll
      for (int g = 0; g < 8; ++g) {
        f16x8 v;
#pragma unroll
        for (int e = 0; e < 8; ++e) {
          int r = halfsel * 64 + g * 8 + e;
          v[e] = Ct[r * 128 + (c ^ ((r & 7) << 3))];
        }
        *(f16x8*)(dst + g * 8) = v;
      }
    }
  } else {
    // out-projection: f32 output, lane-coalesced 4B stores (64B runs)
#pragma unroll
    for (int i = 0; i < 4; ++i) {
#pragma unroll
      for (int j = 0; j < 4; ++j) {
#pragma unroll
        for (int r = 0; r < 4; ++r) {
          int grow = m0 + wr * 64 + i * 16 + ((lane >> 4) << 2) + r;
          int gcol = n0 + wc * 64 + j * 16 + (lane & 15);
          outF[(size_t)grow * 1024 + gcol] = acc[i][j][r] + bias[gcol];
        }
      }
    }
  }
}

// ---------------- flash attention: 32x32 swapped, LDS-staged, split-K x2 ----------------
__global__ __launch_bounds__(256, 4) void flash_k(
    const f16* __restrict__ qh, const f16* __restrict__ kh, const f16* __restrict__ vt,
    f16* __restrict__ op, float2* __restrict__ mlbuf) {
  __shared__ f16 Ks[2][64 * 64];
  __shared__ f16 Vs[2][64 * 64];   // Vs[dk][key]
  int tid = threadIdx.x, wid = tid >> 6, lane = tid & 63;
  int l31 = lane & 31, hi = lane >> 5;
  int qt = blockIdx.x, h = blockIdx.y, z = blockIdx.z;  // z = b*2 + ks
  int b = z >> 1, ks = z & 1;
  size_t bh = (size_t)b * 16 + h;
  const f16* qp = qh + bh * (2048 * 64);
  const f16* kp = kh + bh * (2048 * 64) + (size_t)ks * 1024 * 64;
  const f16* vp = vt + bh * (64 * 2048) + ks * 1024;
  int qrow = qt * 128 + wid * 32 + l31;

  // Q fragments: qf[kk][e] = Q[qrow][kk*16 + hi*8 + e]
  f16x8 qf[4];
#pragma unroll
  for (int kk = 0; kk < 4; ++kk)
    qf[kk] = *(const f16x8*)(qp + (size_t)qrow * 64 + kk * 16 + hi * 8);

  // staging: tile = 64 rows x 128B = 512 16B-slots; 2 issues per array per thread.
  int srowA = tid >> 3, srowB = srowA + 32;
  int schA = (tid & 7) ^ (srowA & 7);
  int schB = (tid & 7) ^ (srowB & 7);
  const f16* ksrcA = kp + (size_t)srowA * 64 + schA * 8;    // + kt*4096
  const f16* ksrcB = kp + (size_t)srowB * 64 + schB * 8;
  const f16* vsrcA = vp + (size_t)srowA * 2048 + schA * 8;  // + kt*64
  const f16* vsrcB = vp + (size_t)srowB * 2048 + schB * 8;

  // swizzled read byte-offsets (same formula serves K rows=key and V rows=dk)
  int offr[2][4];
#pragma unroll
  for (int kb = 0; kb < 2; ++kb)
#pragma unroll
    for (int kk = 0; kk < 4; ++kk) {
      int row = kb * 32 + l31;
      offr[kb][kk] = (row * 128 + kk * 32 + hi * 16) ^ ((row & 7) << 4);
    }

  float m_ = -1e30f, l_ = 0.f;
  f32x16 oacc[2] = {};

  // prologue: stage tile 0 into buf 0
  gload16(ksrcA, (char*)&Ks[0][0] + tid * 16);
  gload16(ksrcB, (char*)&Ks[0][0] + 4096 + tid * 16);
  gload16(vsrcA, (char*)&Vs[0][0] + tid * 16);
  gload16(vsrcB, (char*)&Vs[0][0] + 4096 + tid * 16);
  __syncthreads();

  int cur = 0;
  for (int kt = 0; kt < 16; ++kt) {
    if (kt + 1 < 16) {  // issue next-tile loads before compute
      gload16(ksrcA + (size_t)(kt + 1) * 4096, (char*)&Ks[cur ^ 1][0] + tid * 16);
      gload16(ksrcB + (size_t)(kt + 1) * 4096, (char*)&Ks[cur ^ 1][0] + 4096 + tid * 16);
      gload16(vsrcA + (size_t)(kt + 1) * 64, (char*)&Vs[cur ^ 1][0] + tid * 16);
      gload16(vsrcB + (size_t)(kt + 1) * 64, (char*)&Vs[cur ^ 1][0] + 4096 + tid * 16);
    }

    // QK^T (S^T: lane owns one q-row, 32 scores across regs + cross-half)
    const char* kbase = (const char*)&Ks[cur][0];
    f32x16 sacc[2] = {};
#pragma unroll
    for (int kb = 0; kb < 2; ++kb)
#pragma unroll
      for (int kk = 0; kk < 4; ++kk) {
        f16x8 af = *(const f16x8*)(kbase + offr[kb][kk]);
        sacc[kb] = __builtin_amdgcn_mfma_f32_32x32x16_f16(af, qf[kk], sacc[kb], 0, 0, 0);
      }

    // tree max over 32 local scores, then cross-half
    float t16[16];
#pragma unroll
    for (int i = 0; i < 16; ++i) t16[i] = fmaxf(sacc[0][i], sacc[1][i]);
#pragma unroll
    for (int s = 8; s; s >>= 1)
#pragma unroll
      for (int i = 0; i < s; ++i) t16[i] = fmaxf(t16[i], t16[i + s]);
    float pmax = fmaxf(t16[0], __shfl_xor(t16[0], 32));

    // defer-max (T13, THR=8): wave-uniform rescale skip
    if (!__all(pmax <= m_ + 8.0f)) {
      float mn = fmaxf(m_, pmax);
      float al = __builtin_amdgcn_exp2f(m_ - mn);
      m_ = mn;
      l_ *= al;
#pragma unroll
      for (int mb = 0; mb < 2; ++mb)
#pragma unroll
        for (int i = 0; i < 16; ++i) oacc[mb][i] *= al;
    }

    // P = 2^(s - m), tree sum
#pragma unroll
    for (int kb = 0; kb < 2; ++kb)
#pragma unroll
      for (int i = 0; i < 16; ++i)
        sacc[kb][i] = __builtin_amdgcn_exp2f(sacc[kb][i] - m_);
#pragma unroll
    for (int i = 0; i < 16; ++i) t16[i] = sacc[0][i] + sacc[1][i];
#pragma unroll
    for (int s = 8; s; s >>= 1)
#pragma unroll
      for (int i = 0; i < s; ++i) t16[i] += t16[i + s];
    l_ += t16[0] + __shfl_xor(t16[0], 32);

    // pack P^T fragments: pa[kk] slot (hi,e) = key 16kk + 8hi + e (fp16)
    f16x8 pa[4];
#pragma unroll
    for (int kk = 0; kk < 4; ++kk) {
      int kb = kk >> 1, c8 = (kk & 1) * 8;
      float wA = b32(__builtin_amdgcn_cvt_pkrtz(sacc[kb][c8 + 0], sacc[kb][c8 + 1]));
      float wB = b32(__builtin_amdgcn_cvt_pkrtz(sacc[kb][c8 + 2], sacc[kb][c8 + 3]));
      float wC = b32(__builtin_amdgcn_cvt_pkrtz(sacc[kb][c8 + 4], sacc[kb][c8 + 5]));
      float wD = b32(__builtin_amdgcn_cvt_pkrtz(sacc[kb][c8 + 6], sacc[kb][c8 + 7]));
      float oA = __shfl_xor(wA, 32), oB = __shfl_xor(wB, 32);
      float oC = __shfl_xor(wC, 32), oD = __shfl_xor(wD, 32);
      float4 ff;
      ff.x = hi ? oC : wA;
      ff.y = hi ? oD : wB;
      ff.z = hi ? wC : oA;
      ff.w = hi ? wD : oB;
      pa[kk] = __builtin_bit_cast(f16x8, ff);
    }

    // PV: out^T += V^T x P^T
    const char* vbase = (const char*)&Vs[cur][0];
#pragma unroll
    for (int kk = 0; kk < 4; ++kk)
#pragma unroll
      for (int mb = 0; mb < 2; ++mb) {
        f16x8 av = *(const f16x8*)(vbase + offr[mb][kk]);
        oacc[mb] = __builtin_amdgcn_mfma_f32_32x32x16_f16(av, pa[kk], oacc[mb], 0, 0, 0);
      }

    __syncthreads();
    cur ^= 1;
  }

  // epilogue: normalized partial O + (m,l)
  float inv = 1.f / l_;
  f16* orow = op + (((size_t)z * 16 + h) * 2048 + qrow) * 64;
#pragma unroll
  for (int mb = 0; mb < 2; ++mb)
#pragma unroll
    for (int g = 0; g < 4; ++g) {
      uint2 st;
      st.x = u32(__builtin_amdgcn_cvt_pkrtz(oacc[mb][4 * g + 0] * inv, oacc[mb][4 * g + 1] * inv));
      st.y = u32(__builtin_amdgcn_cvt_pkrtz(oacc[mb][4 * g + 2] * inv, oacc[mb][4 * g + 3] * inv));
      *(uint2*)(orow + mb * 32 + g * 8 + hi * 4) = st;
    }
  if (hi == 0)
    mlbuf[((size_t)z * 16 + h) * 2048 + qrow] = make_float2(m_, l_);
}

// ---------------- combine the two split-K halves ----------------
__global__ __launch_bounds__(256) void combine_k(
    const f16* __restrict__ op, const float2* __restrict__ ml, f16* __restrict__ attnout) {
  int t = blockIdx.x * 256 + threadIdx.x;
  int row = t >> 3, c8 = t & 7;
  int b = row >> 15, h = (row >> 11) & 15, qrow = row & 2047;
  size_t i0 = ((size_t)(b * 2 + 0) * 16 + h) * 2048 + qrow;
  size_t i1 = ((size_t)(b * 2 + 1) * 16 + h) * 2048 + qrow;
  float2 a = ml[i0], c = ml[i1];
  float M = fmaxf(a.x, c.x);
  float w1 = a.y * __builtin_amdgcn_exp2f(a.x - M);
  float w2 = c.y * __builtin_amdgcn_exp2f(c.x - M);
  float inv = 1.f / (w1 + w2);
  w1 *= inv; w2 *= inv;
  f16x8 o1 = *(const f16x8*)(op + i0 * 64 + c8 * 8);
  f16x8 o2 = *(const f16x8*)(op + i1 * 64 + c8 * 8);
  f16x8 o;
#pragma unroll
  for (int e = 0; e < 8; ++e)
    o[e] = (f16)(w1 * (float)o1[e] + w2 * (float)o2[e]);
  *(f16x8*)(attnout + ((size_t)b * 2048 + qrow) * 1024 + h * 64 + c8 * 8) = o;
}

extern "C" void kernel_launch(void* const* d_in, const int* in_sizes, int n_in,
                              void* d_out, int out_size, void* d_ws, size_t ws_size,
                              hipStream_t stream) {
  (void)in_sizes; (void)n_in; (void)out_size; (void)ws_size;
  const float* query = (const float*)d_in[0];
  const float* key   = (const float*)d_in[1];
  const float* value = (const float*)d_in[2];
  const float* wq = (const float*)d_in[3];
  const float* bq = (const float*)d_in[4];
  const float* wk = (const float*)d_in[5];
  const float* bk = (const float*)d_in[6];
  const float* wv = (const float*)d_in[7];
  const float* bv = (const float*)d_in[8];
  const float* wo = (const float*)d_in[9];
  const float* bo = (const float*)d_in[10];
  const float* cosT = (const float*)d_in[11];
  const float* sinT = (const float*)d_in[12];
  float* out = (float*)d_out;
  f16* ws = (f16*)d_ws;
  const size_t SEG = (size_t)4 * 1024 * 1024;
  f16* Xh = ws;                       // 3*SEG halves (query/key/value fp16)
  f16* Wh = ws + 3 * SEG;             // 4*1M halves (wq,wk,wv,wo fp16)
  f16* qh = ws + 16u * 1024 * 1024;   // SEG
  f16* kh = qh + SEG;                 // SEG
  f16* vt = kh + SEG;                 // SEG (total 56 MB)
  f16* attnout = ws;                  // aliases queryh (dead after projections)
  f16* op = ws + SEG;                 // aliases keyh+valueh (dead): 8M halves
  float2* mlb = (float2*)(ws + 12u * 1024 * 1024);  // aliases wqh (dead): 1MB

  convert_k<<<8192, 256, 0, stream>>>(query, key, value, wq, wk, wv, wo, ws);
  gemm_k<1><<<dim3(8, 32, 3), 256, 0, stream>>>(Xh, Wh, bq, bk, bv, cosT, sinT,
                                                qh, kh, vt, nullptr);
  flash_k<<<dim3(16, 16, 4), 256, 0, stream>>>(qh, kh, vt, op, mlb);
  combine_k<<<2048, 256, 0, stream>>>(op, mlb, attnout);
  gemm_k<0><<<dim3(8, 32, 1), 256, 0, stream>>>(attnout, Wh + 3u * 1024 * 1024, bo,
                                                nullptr, nullptr, nullptr, nullptr,
                                                nullptr, nullptr, nullptr, out);
}

// Round 9
// 155.062 us; speedup vs baseline: 1.0991x; 1.0191x over previous
//
#include <hip/hip_runtime.h>
#include <hip/hip_fp16.h>

typedef _Float16 f16;
using f16x8 = __attribute__((ext_vector_type(8))) _Float16;
using h2 = __attribute__((ext_vector_type(2))) __fp16;   // cvt_pkrtz return type
using f32x4 = __attribute__((ext_vector_type(4))) float;
using f32x16 = __attribute__((ext_vector_type(16))) float;

#define LOG2E 1.4426950408889634f

__device__ __forceinline__ void gload16(const void* g, void* l) {
  __builtin_amdgcn_global_load_lds(
      (const __attribute__((address_space(1))) void*)g,
      (__attribute__((address_space(3))) void*)l, 16, 0, 0);
}

__device__ __forceinline__ float b32(h2 x) { return __builtin_bit_cast(float, x); }
__device__ __forceinline__ unsigned u32(h2 x) { return __builtin_bit_cast(unsigned, x); }

// ---------------- convert f32 -> fp16 ----------------
// ws layout (halves): [queryh 4M][keyh 4M][valueh 4M][wqh 1M][wkh 1M][wvh 1M][woh 1M]
__global__ __launch_bounds__(256) void convert_k(
    const float* __restrict__ q, const float* __restrict__ k, const float* __restrict__ v,
    const float* __restrict__ wq, const float* __restrict__ wk,
    const float* __restrict__ wv, const float* __restrict__ wo,
    f16* __restrict__ dst) {
  const size_t SEG = (size_t)4 * 1024 * 1024;
  size_t i = ((size_t)blockIdx.x * 256 + threadIdx.x) * 8;
  const float* src; size_t off;
  if (i < SEG)            { src = q;  off = i; }
  else if (i < 2 * SEG)   { src = k;  off = i - SEG; }
  else if (i < 3 * SEG)   { src = v;  off = i - 2 * SEG; }
  else {
    size_t wi = i - 3 * SEG;
    int s = (int)(wi >> 20);
    src = (s == 0) ? wq : (s == 1) ? wk : (s == 2) ? wv : wo;
    off = wi & ((1u << 20) - 1);
  }
  float4 a = *(const float4*)(src + off);
  float4 b = *(const float4*)(src + off + 4);
  f16x8 o;
  o[0] = (f16)a.x; o[1] = (f16)a.y; o[2] = (f16)a.z; o[3] = (f16)a.w;
  o[4] = (f16)b.x; o[5] = (f16)b.y; o[6] = (f16)b.z; o[7] = (f16)b.w;
  *(f16x8*)(dst + i) = o;
}

// ---------------- GEMM: C = A @ W^T (+bias), 128x128 tile, BK=32 ----------------
// 2-phase dbuf with COUNTED vmcnt (loads stay in flight across barriers).
// XCD-swizzled block mapping; LDS-staged wide-store epilogue for QKV path.
template <int QKV>
__global__ __launch_bounds__(256) void gemm_k(
    const f16* __restrict__ Abase, const f16* __restrict__ Wbase,
    const float* __restrict__ b0, const float* __restrict__ b1, const float* __restrict__ b2,
    const float* __restrict__ cosT, const float* __restrict__ sinT,
    f16* __restrict__ qh, f16* __restrict__ kh, f16* __restrict__ vt,
    float* __restrict__ outF) {
  __shared__ f16 sm[4][128 * 32];   // As = sm[0..1], Bs = sm[2..3]; epilogue reuses all 32KB
  int tid = threadIdx.x, wid = tid >> 6, lane = tid & 63;
  int z = QKV ? blockIdx.z : 0;
  const f16* A = Abase + (size_t)z * (4u * 1024 * 1024);
  const f16* W = Wbase + (size_t)z * (1024u * 1024);

  // T1: XCD-aware swizzle. 256 blocks/z, 8 XCDs; each XCD gets 4 m-panels x all 8 n-blocks.
  int lid = blockIdx.x + (blockIdx.y << 3);
  int xcd = lid & 7, q = lid >> 3;
  int m0 = (xcd * 4 + (q & 3)) * 128;
  int n0 = (q >> 2) * 128;
  int wr = wid >> 1, wc = wid & 1;
  f32x4 acc[4][4] = {};

  // staging addresses (kt-invariant): thread stages 16B of row (tid>>2), slot XOR-swizzled
  int srow = tid >> 2;
  int sslot = (tid & 3) ^ (srow & 3);
  const f16* asrc0 = A + (size_t)(m0 + srow) * 1024 + sslot * 8;
  const f16* asrc1 = A + (size_t)(m0 + 64 + srow) * 1024 + sslot * 8;
  const f16* bsrc0 = W + (size_t)(n0 + srow) * 1024 + sslot * 8;
  const f16* bsrc1 = W + (size_t)(n0 + 64 + srow) * 1024 + sslot * 8;

  // frag read offsets (halves, kt-invariant)
  int aoff[4], boff[4];
#pragma unroll
  for (int i = 0; i < 4; ++i) {
    int row = wr * 64 + i * 16 + (lane & 15);
    aoff[i] = row * 32 + (((lane >> 4) ^ (row & 3)) * 8);
    int col = wc * 64 + i * 16 + (lane & 15);
    boff[i] = col * 32 + (((lane >> 4) ^ (col & 3)) * 8);
  }

  // prologue: stage K-step 0 into buf 0 (4 loads in flight)
  gload16(asrc0, (void*)(&sm[0][0] + wid * 512));
  gload16(asrc1, (void*)(&sm[0][0] + 2048 + wid * 512));
  gload16(bsrc0, (void*)(&sm[2][0] + wid * 512));
  gload16(bsrc1, (void*)(&sm[2][0] + 2048 + wid * 512));

  int cur = 0;
  for (int kt = 0; kt < 32; ++kt) {
    if (kt < 31) {  // issue next K-step loads; keep them in flight across barriers
      int k0 = (kt + 1) * 32;
      gload16(asrc0 + k0, (void*)(&sm[cur ^ 1][0] + wid * 512));
      gload16(asrc1 + k0, (void*)(&sm[cur ^ 1][0] + 2048 + wid * 512));
      gload16(bsrc0 + k0, (void*)(&sm[2 + (cur ^ 1)][0] + wid * 512));
      gload16(bsrc1 + k0, (void*)(&sm[2 + (cur ^ 1)][0] + 2048 + wid * 512));
      asm volatile("s_waitcnt vmcnt(4)" ::: "memory");  // tile kt's 4 loads done
    } else {
      asm volatile("s_waitcnt vmcnt(0)" ::: "memory");
    }
    __builtin_amdgcn_s_barrier();          // all waves' tile-kt stages visible
    __builtin_amdgcn_sched_barrier(0);     // fence: no ds_read hoisting (rule #18)
    f16x8 af[4], bf[4];
#pragma unroll
    for (int i = 0; i < 4; ++i) {
      af[i] = *(const f16x8*)(&sm[cur][0] + aoff[i]);
      bf[i] = *(const f16x8*)(&sm[2 + cur][0] + boff[i]);
    }
#pragma unroll
    for (int i = 0; i < 4; ++i)
#pragma unroll
      for (int j = 0; j < 4; ++j)
        acc[i][j] = __builtin_amdgcn_mfma_f32_16x16x32_f16(af[i], bf[j], acc[i][j], 0, 0, 0);
    __builtin_amdgcn_s_barrier();          // protect buf from next iteration's stage
    cur ^= 1;
  }

  const float* bias = QKV ? (z == 0 ? b0 : (z == 1 ? b1 : b2)) : b0;

  if (QKV) {
    // ---- phase 1: compute bias/RoPE, stage f16 tile into LDS (chunk-XOR swizzled) ----
    f16* Ct = &sm[0][0];  // [128][128] f16 = 32KB
#pragma unroll
    for (int i = 0; i < 4; ++i) {
#pragma unroll
      for (int j = 0; j < 4; ++j) {
#pragma unroll
        for (int r = 0; r < 4; ++r) {
          int row_l = wr * 64 + i * 16 + ((lane >> 4) << 2) + r;
          int col_l = wc * 64 + j * 16 + (lane & 15);
          int gcol = n0 + col_l;
          float val = acc[i][j][r] + bias[gcol];
          if (z < 2) {
            int s = (m0 + row_l) & 2047;
            float pr = __shfl_xor(val, 1);
            int j2 = gcol >> 1;
            float c = cosT[s * 512 + j2], sn = sinT[s * 512 + j2];
            val = (lane & 1) ? (c * val + sn * pr) : (c * val - sn * pr);
            if (z == 0) val *= 0.125f * LOG2E;  // fold 1/sqrt(DK) and log2(e) into Q
          }
          Ct[row_l * 128 + (col_l ^ ((row_l & 7) << 3))] = (f16)val;
        }
      }
    }
    __syncthreads();
    // ---- phase 2: wide coalesced stores ----
    int bb = m0 >> 11, sbase = m0 & 2047;
    if (z < 2) {
      // qh/kh [bh][s][dk]: thread owns one half-row (64 dk of one head)
      int row = tid >> 1, halfsel = tid & 1;
      int h = (n0 >> 6) + halfsel;
      f16* dst = (z == 0 ? qh : kh) +
                 (((size_t)bb * 16 + h) * 2048 + sbase + row) * 64;
#pragma unroll
      for (int ch = 0; ch < 8; ++ch) {
        int c = halfsel * 64 + ch * 8;
        f16x8 v = *(const f16x8*)(Ct + row * 128 + (c ^ ((row & 7) << 3)));
        *(f16x8*)(dst + ch * 8) = v;
      }
    } else {
      // vt [bh][dk][s]: thread owns one column (dk) x 128 rows (s); 8 x 16B contiguous stores
      int c = tid & 127, halfsel = tid >> 7;
      int h = (n0 >> 6) + (c >> 6), dk = c & 63;
      f16* dst = vt + (((size_t)bb * 16 + h) * 64 + dk) * 2048 + sbase + halfsel * 64;
#pragma unroll
      for (int g = 0; g < 8; ++g) {
        f16x8 v;
#pragma unroll
        for (int e = 0; e < 8; ++e) {
          int r = halfsel * 64 + g * 8 + e;
          v[e] = Ct[r * 128 + (c ^ ((r & 7) << 3))];
        }
        *(f16x8*)(dst + g * 8) = v;
      }
    }
  } else {
    // out-projection: f32 output, lane-coalesced 4B stores (64B runs)
#pragma unroll
    for (int i = 0; i < 4; ++i) {
#pragma unroll
      for (int j = 0; j < 4; ++j) {
#pragma unroll
        for (int r = 0; r < 4; ++r) {
          int grow = m0 + wr * 64 + i * 16 + ((lane >> 4) << 2) + r;
          int gcol = n0 + wc * 64 + j * 16 + (lane & 15);
          outF[(size_t)grow * 1024 + gcol] = acc[i][j][r] + bias[gcol];
        }
      }
    }
  }
}

// ---------------- flash attention: 32x32 swapped, LDS-staged, split-K x2 ----------------
// Counted-vmcnt double buffer: prefetch stays in flight across both barriers.
__global__ __launch_bounds__(256, 4) void flash_k(
    const f16* __restrict__ qh, const f16* __restrict__ kh, const f16* __restrict__ vt,
    f16* __restrict__ op, float2* __restrict__ mlbuf) {
  __shared__ f16 Ks[2][64 * 64];
  __shared__ f16 Vs[2][64 * 64];   // Vs[dk][key]
  int tid = threadIdx.x, wid = tid >> 6, lane = tid & 63;
  int l31 = lane & 31, hi = lane >> 5;
  int qt = blockIdx.x, h = blockIdx.y, z = blockIdx.z;  // z = b*2 + ks
  int b = z >> 1, ks = z & 1;
  size_t bh = (size_t)b * 16 + h;
  const f16* qp = qh + bh * (2048 * 64);
  const f16* kp = kh + bh * (2048 * 64) + (size_t)ks * 1024 * 64;
  const f16* vp = vt + bh * (64 * 2048) + ks * 1024;
  int qrow = qt * 128 + wid * 32 + l31;

  // Q fragments: qf[kk][e] = Q[qrow][kk*16 + hi*8 + e]
  f16x8 qf[4];
#pragma unroll
  for (int kk = 0; kk < 4; ++kk)
    qf[kk] = *(const f16x8*)(qp + (size_t)qrow * 64 + kk * 16 + hi * 8);

  // staging: tile = 64 rows x 128B = 512 16B-slots; 2 issues per array per thread.
  int srowA = tid >> 3, srowB = srowA + 32;
  int schA = (tid & 7) ^ (srowA & 7);
  int schB = (tid & 7) ^ (srowB & 7);
  const f16* ksrcA = kp + (size_t)srowA * 64 + schA * 8;    // + kt*4096
  const f16* ksrcB = kp + (size_t)srowB * 64 + schB * 8;
  const f16* vsrcA = vp + (size_t)srowA * 2048 + schA * 8;  // + kt*64
  const f16* vsrcB = vp + (size_t)srowB * 2048 + schB * 8;

  // swizzled read byte-offsets (same formula serves K rows=key and V rows=dk)
  int offr[2][4];
#pragma unroll
  for (int kb = 0; kb < 2; ++kb)
#pragma unroll
    for (int kk = 0; kk < 4; ++kk) {
      int row = kb * 32 + l31;
      offr[kb][kk] = (row * 128 + kk * 32 + hi * 16) ^ ((row & 7) << 4);
    }

  float m_ = -1e30f, l_ = 0.f;
  f32x16 oacc[2] = {};

  // prologue: stage tile 0 into buf 0 (4 loads in flight)
  gload16(ksrcA, (char*)&Ks[0][0] + tid * 16);
  gload16(ksrcB, (char*)&Ks[0][0] + 4096 + tid * 16);
  gload16(vsrcA, (char*)&Vs[0][0] + tid * 16);
  gload16(vsrcB, (char*)&Vs[0][0] + 4096 + tid * 16);

  int cur = 0;
  for (int kt = 0; kt < 16; ++kt) {
    if (kt < 15) {  // issue next-tile loads; keep in flight across barriers
      gload16(ksrcA + (size_t)(kt + 1) * 4096, (char*)&Ks[cur ^ 1][0] + tid * 16);
      gload16(ksrcB + (size_t)(kt + 1) * 4096, (char*)&Ks[cur ^ 1][0] + 4096 + tid * 16);
      gload16(vsrcA + (size_t)(kt + 1) * 64, (char*)&Vs[cur ^ 1][0] + tid * 16);
      gload16(vsrcB + (size_t)(kt + 1) * 64, (char*)&Vs[cur ^ 1][0] + 4096 + tid * 16);
      asm volatile("s_waitcnt vmcnt(4)" ::: "memory");  // tile kt's 4 loads done
    } else {
      asm volatile("s_waitcnt vmcnt(0)" ::: "memory");
    }
    __builtin_amdgcn_s_barrier();          // all waves' tile-kt stages visible
    __builtin_amdgcn_sched_barrier(0);     // fence (rule #18)

    // QK^T (S^T: lane owns one q-row, 32 scores across regs + cross-half)
    const char* kbase = (const char*)&Ks[cur][0];
    f32x16 sacc[2] = {};
#pragma unroll
    for (int kb = 0; kb < 2; ++kb)
#pragma unroll
      for (int kk = 0; kk < 4; ++kk) {
        f16x8 af = *(const f16x8*)(kbase + offr[kb][kk]);
        sacc[kb] = __builtin_amdgcn_mfma_f32_32x32x16_f16(af, qf[kk], sacc[kb], 0, 0, 0);
      }

    // tree max over 32 local scores, then cross-half
    float t16[16];
#pragma unroll
    for (int i = 0; i < 16; ++i) t16[i] = fmaxf(sacc[0][i], sacc[1][i]);
#pragma unroll
    for (int s = 8; s; s >>= 1)
#pragma unroll
      for (int i = 0; i < s; ++i) t16[i] = fmaxf(t16[i], t16[i + s]);
    float pmax = fmaxf(t16[0], __shfl_xor(t16[0], 32));

    // defer-max (T13, THR=8): wave-uniform rescale skip
    if (!__all(pmax <= m_ + 8.0f)) {
      float mn = fmaxf(m_, pmax);
      float al = __builtin_amdgcn_exp2f(m_ - mn);
      m_ = mn;
      l_ *= al;
#pragma unroll
      for (int mb = 0; mb < 2; ++mb)
#pragma unroll
        for (int i = 0; i < 16; ++i) oacc[mb][i] *= al;
    }

    // P = 2^(s - m), tree sum
#pragma unroll
    for (int kb = 0; kb < 2; ++kb)
#pragma unroll
      for (int i = 0; i < 16; ++i)
        sacc[kb][i] = __builtin_amdgcn_exp2f(sacc[kb][i] - m_);
#pragma unroll
    for (int i = 0; i < 16; ++i) t16[i] = sacc[0][i] + sacc[1][i];
#pragma unroll
    for (int s = 8; s; s >>= 1)
#pragma unroll
      for (int i = 0; i < s; ++i) t16[i] += t16[i + s];
    l_ += t16[0] + __shfl_xor(t16[0], 32);

    // pack P^T fragments: pa[kk] slot (hi,e) = key 16kk + 8hi + e (fp16)
    f16x8 pa[4];
#pragma unroll
    for (int kk = 0; kk < 4; ++kk) {
      int kb = kk >> 1, c8 = (kk & 1) * 8;
      float wA = b32(__builtin_amdgcn_cvt_pkrtz(sacc[kb][c8 + 0], sacc[kb][c8 + 1]));
      float wB = b32(__builtin_amdgcn_cvt_pkrtz(sacc[kb][c8 + 2], sacc[kb][c8 + 3]));
      float wC = b32(__builtin_amdgcn_cvt_pkrtz(sacc[kb][c8 + 4], sacc[kb][c8 + 5]));
      float wD = b32(__builtin_amdgcn_cvt_pkrtz(sacc[kb][c8 + 6], sacc[kb][c8 + 7]));
      float oA = __shfl_xor(wA, 32), oB = __shfl_xor(wB, 32);
      float oC = __shfl_xor(wC, 32), oD = __shfl_xor(wD, 32);
      float4 ff;
      ff.x = hi ? oC : wA;
      ff.y = hi ? oD : wB;
      ff.z = hi ? wC : oA;
      ff.w = hi ? wD : oB;
      pa[kk] = __builtin_bit_cast(f16x8, ff);
    }

    // PV: out^T += V^T x P^T
    const char* vbase = (const char*)&Vs[cur][0];
#pragma unroll
    for (int kk = 0; kk < 4; ++kk)
#pragma unroll
      for (int mb = 0; mb < 2; ++mb) {
        f16x8 av = *(const f16x8*)(vbase + offr[mb][kk]);
        oacc[mb] = __builtin_amdgcn_mfma_f32_32x32x16_f16(av, pa[kk], oacc[mb], 0, 0, 0);
      }

    __builtin_amdgcn_s_barrier();          // protect buf from next iteration's stage
    cur ^= 1;
  }

  // epilogue: normalized partial O + (m,l)
  float inv = 1.f / l_;
  f16* orow = op + (((size_t)z * 16 + h) * 2048 + qrow) * 64;
#pragma unroll
  for (int mb = 0; mb < 2; ++mb)
#pragma unroll
    for (int g = 0; g < 4; ++g) {
      uint2 st;
      st.x = u32(__builtin_amdgcn_cvt_pkrtz(oacc[mb][4 * g + 0] * inv, oacc[mb][4 * g + 1] * inv));
      st.y = u32(__builtin_amdgcn_cvt_pkrtz(oacc[mb][4 * g + 2] * inv, oacc[mb][4 * g + 3] * inv));
      *(uint2*)(orow + mb * 32 + g * 8 + hi * 4) = st;
    }
  if (hi == 0)
    mlbuf[((size_t)z * 16 + h) * 2048 + qrow] = make_float2(m_, l_);
}

// ---------------- combine the two split-K halves ----------------
__global__ __launch_bounds__(256) void combine_k(
    const f16* __restrict__ op, const float2* __restrict__ ml, f16* __restrict__ attnout) {
  int t = blockIdx.x * 256 + threadIdx.x;
  int row = t >> 3, c8 = t & 7;
  int b = row >> 15, h = (row >> 11) & 15, qrow = row & 2047;
  size_t i0 = ((size_t)(b * 2 + 0) * 16 + h) * 2048 + qrow;
  size_t i1 = ((size_t)(b * 2 + 1) * 16 + h) * 2048 + qrow;
  float2 a = ml[i0], c = ml[i1];
  float M = fmaxf(a.x, c.x);
  float w1 = a.y * __builtin_amdgcn_exp2f(a.x - M);
  float w2 = c.y * __builtin_amdgcn_exp2f(c.x - M);
  float inv = 1.f / (w1 + w2);
  w1 *= inv; w2 *= inv;
  f16x8 o1 = *(const f16x8*)(op + i0 * 64 + c8 * 8);
  f16x8 o2 = *(const f16x8*)(op + i1 * 64 + c8 * 8);
  f16x8 o;
#pragma unroll
  for (int e = 0; e < 8; ++e)
    o[e] = (f16)(w1 * (float)o1[e] + w2 * (float)o2[e]);
  *(f16x8*)(attnout + ((size_t)b * 2048 + qrow) * 1024 + h * 64 + c8 * 8) = o;
}

extern "C" void kernel_launch(void* const* d_in, const int* in_sizes, int n_in,
                              void* d_out, int out_size, void* d_ws, size_t ws_size,
                              hipStream_t stream) {
  (void)in_sizes; (void)n_in; (void)out_size; (void)ws_size;
  const float* query = (const float*)d_in[0];
  const float* key   = (const float*)d_in[1];
  const float* value = (const float*)d_in[2];
  const float* wq = (const float*)d_in[3];
  const float* bq = (const float*)d_in[4];
  const float* wk = (const float*)d_in[5];
  const float* bk = (const float*)d_in[6];
  const float* wv = (const float*)d_in[7];
  const float* bv = (const float*)d_in[8];
  const float* wo = (const float*)d_in[9];
  const float* bo = (const float*)d_in[10];
  const float* cosT = (const float*)d_in[11];
  const float* sinT = (const float*)d_in[12];
  float* out = (float*)d_out;
  f16* ws = (f16*)d_ws;
  const size_t SEG = (size_t)4 * 1024 * 1024;
  f16* Xh = ws;                       // 3*SEG halves (query/key/value fp16)
  f16* Wh = ws + 3 * SEG;             // 4*1M halves (wq,wk,wv,wo fp16)
  f16* qh = ws + 16u * 1024 * 1024;   // SEG
  f16* kh = qh + SEG;                 // SEG
  f16* vt = kh + SEG;                 // SEG (total 56 MB)
  f16* attnout = ws;                  // aliases queryh (dead after projections)
  f16* op = ws + SEG;                 // aliases keyh+valueh (dead): 8M halves
  float2* mlb = (float2*)(ws + 12u * 1024 * 1024);  // aliases wqh (dead): 1MB

  convert_k<<<8192, 256, 0, stream>>>(query, key, value, wq, wk, wv, wo, ws);
  gemm_k<1><<<dim3(8, 32, 3), 256, 0, stream>>>(Xh, Wh, bq, bk, bv, cosT, sinT,
                                                qh, kh, vt, nullptr);
  flash_k<<<dim3(16, 16, 4), 256, 0, stream>>>(qh, kh, vt, op, mlb);
  combine_k<<<2048, 256, 0, stream>>>(op, mlb, attnout);
  gemm_k<0><<<dim3(8, 32, 1), 256, 0, stream>>>(attnout, Wh + 3u * 1024 * 1024, bo,
                                                nullptr, nullptr, nullptr, nullptr,
                                                nullptr, nullptr, nullptr, out);
}

// Round 11
// 144.830 us; speedup vs baseline: 1.1768x; 1.0706x over previous
//
#include <hip/hip_runtime.h>
#include <hip/hip_fp16.h>

typedef _Float16 f16;
using f16x8 = __attribute__((ext_vector_type(8))) _Float16;
using h2 = __attribute__((ext_vector_type(2))) __fp16;   // cvt_pkrtz return type
using f32x4 = __attribute__((ext_vector_type(4))) float;
using f32x16 = __attribute__((ext_vector_type(16))) float;

#define LOG2E 1.4426950408889634f

__device__ __forceinline__ void gload16(const void* g, void* l) {
  __builtin_amdgcn_global_load_lds(
      (const __attribute__((address_space(1))) void*)g,
      (__attribute__((address_space(3))) void*)l, 16, 0, 0);
}

__device__ __forceinline__ float b32(h2 x) { return __builtin_bit_cast(float, x); }
__device__ __forceinline__ unsigned u32(h2 x) { return __builtin_bit_cast(unsigned, x); }

// ---------------- convert f32 -> fp16 ----------------
// ws layout (halves): [queryh 4M][keyh 4M][valueh 4M][wqh 1M][wkh 1M][wvh 1M][woh 1M]
__global__ __launch_bounds__(256) void convert_k(
    const float* __restrict__ q, const float* __restrict__ k, const float* __restrict__ v,
    const float* __restrict__ wq, const float* __restrict__ wk,
    const float* __restrict__ wv, const float* __restrict__ wo,
    f16* __restrict__ dst) {
  const size_t SEG = (size_t)4 * 1024 * 1024;
  size_t i = ((size_t)blockIdx.x * 256 + threadIdx.x) * 8;
  const float* src; size_t off;
  if (i < SEG)            { src = q;  off = i; }
  else if (i < 2 * SEG)   { src = k;  off = i - SEG; }
  else if (i < 3 * SEG)   { src = v;  off = i - 2 * SEG; }
  else {
    size_t wi = i - 3 * SEG;
    int s = (int)(wi >> 20);
    src = (s == 0) ? wq : (s == 1) ? wk : (s == 2) ? wv : wo;
    off = wi & ((1u << 20) - 1);
  }
  float4 a = *(const float4*)(src + off);
  float4 b = *(const float4*)(src + off + 4);
  f16x8 o;
  o[0] = (f16)a.x; o[1] = (f16)a.y; o[2] = (f16)a.z; o[3] = (f16)a.w;
  o[4] = (f16)b.x; o[5] = (f16)b.y; o[6] = (f16)b.z; o[7] = (f16)b.w;
  *(f16x8*)(dst + i) = o;
}

// ---------------- GEMM: C = A @ W^T (+bias), 128x128 tile, BK=32 ----------------
// 3-deep LDS pipeline with counted vmcnt(8): ~2 compute-phases of latency coverage.
// XCD-swizzled block mapping; LDS-staged wide-store epilogue for QKV path.
template <int QKV>
__global__ __launch_bounds__(256) void gemm_k(
    const f16* __restrict__ Abase, const f16* __restrict__ Wbase,
    const float* __restrict__ b0, const float* __restrict__ b1, const float* __restrict__ b2,
    const float* __restrict__ cosT, const float* __restrict__ sinT,
    f16* __restrict__ qh, f16* __restrict__ kh, f16* __restrict__ vt,
    float* __restrict__ outF) {
  __shared__ f16 sm[6][128 * 32];   // A bufs 0..2, B bufs 3..5 (48 KB); epilogue reuses 0..3
  int tid = threadIdx.x, wid = tid >> 6, lane = tid & 63;
  int z = QKV ? blockIdx.z : 0;
  const f16* A = Abase + (size_t)z * (4u * 1024 * 1024);
  const f16* W = Wbase + (size_t)z * (1024u * 1024);

  // T1: XCD-aware swizzle. 256 blocks/z, 8 XCDs; each XCD gets 4 m-panels x all 8 n-blocks.
  int lid = blockIdx.x + (blockIdx.y << 3);
  int xcd = lid & 7, q = lid >> 3;
  int m0 = (xcd * 4 + (q & 3)) * 128;
  int n0 = (q >> 2) * 128;
  int wr = wid >> 1, wc = wid & 1;
  f32x4 acc[4][4] = {};

  // staging addresses (kt-invariant): thread stages 16B of row (tid>>2), slot XOR-swizzled
  int srow = tid >> 2;
  int sslot = (tid & 3) ^ (srow & 3);
  const f16* asrc0 = A + (size_t)(m0 + srow) * 1024 + sslot * 8;
  const f16* asrc1 = A + (size_t)(m0 + 64 + srow) * 1024 + sslot * 8;
  const f16* bsrc0 = W + (size_t)(n0 + srow) * 1024 + sslot * 8;
  const f16* bsrc1 = W + (size_t)(n0 + 64 + srow) * 1024 + sslot * 8;

  // frag read offsets (halves, kt-invariant)
  int aoff[4], boff[4];
#pragma unroll
  for (int i = 0; i < 4; ++i) {
    int row = wr * 64 + i * 16 + (lane & 15);
    aoff[i] = row * 32 + (((lane >> 4) ^ (row & 3)) * 8);
    int col = wc * 64 + i * 16 + (lane & 15);
    boff[i] = col * 32 + (((lane >> 4) ^ (col & 3)) * 8);
  }

#define GSTAGE(KT, BUF)                                                        \
  do {                                                                         \
    int k0_ = (KT) * 32;                                                       \
    gload16(asrc0 + k0_, (void*)(&sm[BUF][0] + wid * 512));                    \
    gload16(asrc1 + k0_, (void*)(&sm[BUF][0] + 2048 + wid * 512));             \
    gload16(bsrc0 + k0_, (void*)(&sm[3 + (BUF)][0] + wid * 512));              \
    gload16(bsrc1 + k0_, (void*)(&sm[3 + (BUF)][0] + 2048 + wid * 512));       \
  } while (0)

  // prologue: stage K-steps 0,1 (8 loads in flight)
  GSTAGE(0, 0);
  GSTAGE(1, 1);

  for (int kt = 0; kt < 32; ++kt) {
    int cb = kt % 3;
    if (kt + 2 < 32) {
      GSTAGE(kt + 2, (kt + 2) % 3);
      asm volatile("s_waitcnt vmcnt(8)" ::: "memory");  // kt's 4 loads done
    } else if (kt + 1 < 32) {
      asm volatile("s_waitcnt vmcnt(4)" ::: "memory");
    } else {
      asm volatile("s_waitcnt vmcnt(0)" ::: "memory");
    }
    __builtin_amdgcn_s_barrier();          // all waves' tile-kt stages visible
    __builtin_amdgcn_sched_barrier(0);     // fence: no ds_read hoisting (rule #18)
    f16x8 af[4], bf[4];
#pragma unroll
    for (int i = 0; i < 4; ++i) {
      af[i] = *(const f16x8*)(&sm[cb][0] + aoff[i]);
      bf[i] = *(const f16x8*)(&sm[3 + cb][0] + boff[i]);
    }
#pragma unroll
    for (int i = 0; i < 4; ++i)
#pragma unroll
      for (int j = 0; j < 4; ++j)
        acc[i][j] = __builtin_amdgcn_mfma_f32_16x16x32_f16(af[i], bf[j], acc[i][j], 0, 0, 0);
    __builtin_amdgcn_s_barrier();          // protect this buf from stage(kt+3)
  }
#undef GSTAGE

  const float* bias = QKV ? (z == 0 ? b0 : (z == 1 ? b1 : b2)) : b0;

  if (QKV) {
    // ---- phase 1: compute bias/RoPE, stage f16 tile into LDS (chunk-XOR swizzled) ----
    f16* Ct = &sm[0][0];  // [128][128] f16 = 32KB
#pragma unroll
    for (int i = 0; i < 4; ++i) {
#pragma unroll
      for (int j = 0; j < 4; ++j) {
#pragma unroll
        for (int r = 0; r < 4; ++r) {
          int row_l = wr * 64 + i * 16 + ((lane >> 4) << 2) + r;
          int col_l = wc * 64 + j * 16 + (lane & 15);
          int gcol = n0 + col_l;
          float val = acc[i][j][r] + bias[gcol];
          if (z < 2) {
            int s = (m0 + row_l) & 2047;
            float pr = __shfl_xor(val, 1);
            int j2 = gcol >> 1;
            float c = cosT[s * 512 + j2], sn = sinT[s * 512 + j2];
            val = (lane & 1) ? (c * val + sn * pr) : (c * val - sn * pr);
            if (z == 0) val *= 0.125f * LOG2E;  // fold 1/sqrt(DK) and log2(e) into Q
          }
          Ct[row_l * 128 + (col_l ^ ((row_l & 7) << 3))] = (f16)val;
        }
      }
    }
    __syncthreads();
    // ---- phase 2: wide coalesced stores ----
    int bb = m0 >> 11, sbase = m0 & 2047;
    if (z < 2) {
      // qh/kh [bh][s][dk]: thread owns one half-row (64 dk of one head)
      int row = tid >> 1, halfsel = tid & 1;
      int h = (n0 >> 6) + halfsel;
      f16* dst = (z == 0 ? qh : kh) +
                 (((size_t)bb * 16 + h) * 2048 + sbase + row) * 64;
#pragma unroll
      for (int ch = 0; ch < 8; ++ch) {
        int c = halfsel * 64 + ch * 8;
        f16x8 v = *(const f16x8*)(Ct + row * 128 + (c ^ ((row & 7) << 3)));
        *(f16x8*)(dst + ch * 8) = v;
      }
    } else {
      // vt [bh][dk][s]: thread owns one column (dk) x 128 rows (s); 8 x 16B contiguous stores
      int c = tid & 127, halfsel = tid >> 7;
      int h = (n0 >> 6) + (c >> 6), dk = c & 63;
      f16* dst = vt + (((size_t)bb * 16 + h) * 64 + dk) * 2048 + sbase + halfsel * 64;
#pragma unroll
      for (int g = 0; g < 8; ++g) {
        f16x8 v;
#pragma unroll
        for (int e = 0; e < 8; ++e) {
          int r = halfsel * 64 + g * 8 + e;
          v[e] = Ct[r * 128 + (c ^ ((r & 7) << 3))];
        }
        *(f16x8*)(dst + g * 8) = v;
      }
    }
  } else {
    // out-projection: f32 output, lane-coalesced 4B stores (64B runs)
#pragma unroll
    for (int i = 0; i < 4; ++i) {
#pragma unroll
      for (int j = 0; j < 4; ++j) {
#pragma unroll
        for (int r = 0; r < 4; ++r) {
          int grow = m0 + wr * 64 + i * 16 + ((lane >> 4) << 2) + r;
          int gcol = n0 + wc * 64 + j * 16 + (lane & 15);
          outF[(size_t)grow * 1024 + gcol] = acc[i][j][r] + bias[gcol];
        }
      }
    }
  }
}

// ---------------- flash attention: 32x32 swapped, LDS-staged, split-K x2 ----------------
// Online softmax with defer-max (R8-proven numerics). XCD-chunked 1D grid for K/V L2 locality.
__global__ __launch_bounds__(256, 4) void flash_k(
    const f16* __restrict__ qh, const f16* __restrict__ kh, const f16* __restrict__ vt,
    f16* __restrict__ op, float2* __restrict__ mlbuf) {
  __shared__ f16 Ks[2][64 * 64];
  __shared__ f16 Vs[2][64 * 64];   // Vs[dk][key]
  int tid = threadIdx.x, wid = tid >> 6, lane = tid & 63;
  int l31 = lane & 31, hi = lane >> 5;
  // XCD-chunked decode: bid%8 keyed to (h,z) pair -> each XCD owns 8 pairs x 16 q-tiles.
  int bid = blockIdx.x;
  int xcd = bid & 7, t = bid >> 3;
  int qt = t & 15, phi = t >> 4;
  int p = phi * 8 + xcd;
  int h = p & 15, z = p >> 4;      // z = b*2 + ks
  int b = z >> 1, ks = z & 1;
  size_t bh = (size_t)b * 16 + h;
  const f16* qp = qh + bh * (2048 * 64);
  const f16* kp = kh + bh * (2048 * 64) + (size_t)ks * 1024 * 64;
  const f16* vp = vt + bh * (64 * 2048) + ks * 1024;
  int qrow = qt * 128 + wid * 32 + l31;

  // Q fragments: qf[kk][e] = Q[qrow][kk*16 + hi*8 + e]
  f16x8 qf[4];
#pragma unroll
  for (int kk = 0; kk < 4; ++kk)
    qf[kk] = *(const f16x8*)(qp + (size_t)qrow * 64 + kk * 16 + hi * 8);

  // staging: tile = 64 rows x 128B = 512 16B-slots; 2 issues per array per thread.
  int srowA = tid >> 3, srowB = srowA + 32;
  int schA = (tid & 7) ^ (srowA & 7);
  int schB = (tid & 7) ^ (srowB & 7);
  const f16* ksrcA = kp + (size_t)srowA * 64 + schA * 8;    // + kt*4096
  const f16* ksrcB = kp + (size_t)srowB * 64 + schB * 8;
  const f16* vsrcA = vp + (size_t)srowA * 2048 + schA * 8;  // + kt*64
  const f16* vsrcB = vp + (size_t)srowB * 2048 + schB * 8;

  // swizzled read byte-offsets (same formula serves K rows=key and V rows=dk)
  int offr[2][4];
#pragma unroll
  for (int kb = 0; kb < 2; ++kb)
#pragma unroll
    for (int kk = 0; kk < 4; ++kk) {
      int row = kb * 32 + l31;
      offr[kb][kk] = (row * 128 + kk * 32 + hi * 16) ^ ((row & 7) << 4);
    }

  float m_ = -1e30f, l_ = 0.f;
  f32x16 oacc[2] = {};

  // prologue: stage tile 0 into buf 0 (4 loads in flight)
  gload16(ksrcA, (char*)&Ks[0][0] + tid * 16);
  gload16(ksrcB, (char*)&Ks[0][0] + 4096 + tid * 16);
  gload16(vsrcA, (char*)&Vs[0][0] + tid * 16);
  gload16(vsrcB, (char*)&Vs[0][0] + 4096 + tid * 16);

  int cur = 0;
  for (int kt = 0; kt < 16; ++kt) {
    if (kt < 15) {  // issue next-tile loads; keep in flight across barriers
      gload16(ksrcA + (size_t)(kt + 1) * 4096, (char*)&Ks[cur ^ 1][0] + tid * 16);
      gload16(ksrcB + (size_t)(kt + 1) * 4096, (char*)&Ks[cur ^ 1][0] + 4096 + tid * 16);
      gload16(vsrcA + (size_t)(kt + 1) * 64, (char*)&Vs[cur ^ 1][0] + tid * 16);
      gload16(vsrcB + (size_t)(kt + 1) * 64, (char*)&Vs[cur ^ 1][0] + 4096 + tid * 16);
      asm volatile("s_waitcnt vmcnt(4)" ::: "memory");  // tile kt's 4 loads done
    } else {
      asm volatile("s_waitcnt vmcnt(0)" ::: "memory");
    }
    __builtin_amdgcn_s_barrier();          // all waves' tile-kt stages visible
    __builtin_amdgcn_sched_barrier(0);     // fence (rule #18)

    // QK^T (S^T: lane owns one q-row, 32 scores across regs + cross-half)
    const char* kbase = (const char*)&Ks[cur][0];
    f32x16 sacc[2] = {};
#pragma unroll
    for (int kb = 0; kb < 2; ++kb)
#pragma unroll
      for (int kk = 0; kk < 4; ++kk) {
        f16x8 af = *(const f16x8*)(kbase + offr[kb][kk]);
        sacc[kb] = __builtin_amdgcn_mfma_f32_32x32x16_f16(af, qf[kk], sacc[kb], 0, 0, 0);
      }

    // tree max over 32 local scores, then cross-half
    float t16[16];
#pragma unroll
    for (int i = 0; i < 16; ++i) t16[i] = fmaxf(sacc[0][i], sacc[1][i]);
#pragma unroll
    for (int s = 8; s; s >>= 1)
#pragma unroll
      for (int i = 0; i < s; ++i) t16[i] = fmaxf(t16[i], t16[i + s]);
    float pmax = fmaxf(t16[0], __shfl_xor(t16[0], 32));

    // defer-max (T13, THR=8): wave-uniform rescale skip
    if (!__all(pmax <= m_ + 8.0f)) {
      float mn = fmaxf(m_, pmax);
      float al = __builtin_amdgcn_exp2f(m_ - mn);
      m_ = mn;
      l_ *= al;
#pragma unroll
      for (int mb = 0; mb < 2; ++mb)
#pragma unroll
        for (int i = 0; i < 16; ++i) oacc[mb][i] *= al;
    }

    // P = 2^(s - m), tree sum
#pragma unroll
    for (int kb = 0; kb < 2; ++kb)
#pragma unroll
      for (int i = 0; i < 16; ++i)
        sacc[kb][i] = __builtin_amdgcn_exp2f(sacc[kb][i] - m_);
#pragma unroll
    for (int i = 0; i < 16; ++i) t16[i] = sacc[0][i] + sacc[1][i];
#pragma unroll
    for (int s = 8; s; s >>= 1)
#pragma unroll
      for (int i = 0; i < s; ++i) t16[i] += t16[i + s];
    l_ += t16[0] + __shfl_xor(t16[0], 32);

    // pack P^T fragments: pa[kk] slot (hi,e) = key 16kk + 8hi + e (fp16)
    f16x8 pa[4];
#pragma unroll
    for (int kk = 0; kk < 4; ++kk) {
      int kb = kk >> 1, c8 = (kk & 1) * 8;
      float wA = b32(__builtin_amdgcn_cvt_pkrtz(sacc[kb][c8 + 0], sacc[kb][c8 + 1]));
      float wB = b32(__builtin_amdgcn_cvt_pkrtz(sacc[kb][c8 + 2], sacc[kb][c8 + 3]));
      float wC = b32(__builtin_amdgcn_cvt_pkrtz(sacc[kb][c8 + 4], sacc[kb][c8 + 5]));
      float wD = b32(__builtin_amdgcn_cvt_pkrtz(sacc[kb][c8 + 6], sacc[kb][c8 + 7]));
      float oA = __shfl_xor(wA, 32), oB = __shfl_xor(wB, 32);
      float oC = __shfl_xor(wC, 32), oD = __shfl_xor(wD, 32);
      float4 ff;
      ff.x = hi ? oC : wA;
      ff.y = hi ? oD : wB;
      ff.z = hi ? wC : oA;
      ff.w = hi ? wD : oB;
      pa[kk] = __builtin_bit_cast(f16x8, ff);
    }

    // PV: out^T += V^T x P^T
    const char* vbase = (const char*)&Vs[cur][0];
#pragma unroll
    for (int kk = 0; kk < 4; ++kk)
#pragma unroll
      for (int mb = 0; mb < 2; ++mb) {
        f16x8 av = *(const f16x8*)(vbase + offr[mb][kk]);
        oacc[mb] = __builtin_amdgcn_mfma_f32_32x32x16_f16(av, pa[kk], oacc[mb], 0, 0, 0);
      }

    __builtin_amdgcn_s_barrier();          // protect buf from next iteration's stage
    cur ^= 1;
  }

  // epilogue: normalized partial O + (m,l)
  float inv = 1.f / l_;
  f16* orow = op + (((size_t)z * 16 + h) * 2048 + qrow) * 64;
#pragma unroll
  for (int mb = 0; mb < 2; ++mb)
#pragma unroll
    for (int g = 0; g < 4; ++g) {
      uint2 st;
      st.x = u32(__builtin_amdgcn_cvt_pkrtz(oacc[mb][4 * g + 0] * inv, oacc[mb][4 * g + 1] * inv));
      st.y = u32(__builtin_amdgcn_cvt_pkrtz(oacc[mb][4 * g + 2] * inv, oacc[mb][4 * g + 3] * inv));
      *(uint2*)(orow + mb * 32 + g * 8 + hi * 4) = st;
    }
  if (hi == 0)
    mlbuf[((size_t)z * 16 + h) * 2048 + qrow] = make_float2(m_, l_);
}

// ---------------- combine the two split-K halves ----------------
__global__ __launch_bounds__(256) void combine_k(
    const f16* __restrict__ op, const float2* __restrict__ ml, f16* __restrict__ attnout) {
  int t = blockIdx.x * 256 + threadIdx.x;
  int row = t >> 3, c8 = t & 7;
  int b = row >> 15, h = (row >> 11) & 15, qrow = row & 2047;
  size_t i0 = ((size_t)(b * 2 + 0) * 16 + h) * 2048 + qrow;
  size_t i1 = ((size_t)(b * 2 + 1) * 16 + h) * 2048 + qrow;
  float2 a = ml[i0], c = ml[i1];
  float M = fmaxf(a.x, c.x);
  float w1 = a.y * __builtin_amdgcn_exp2f(a.x - M);
  float w2 = c.y * __builtin_amdgcn_exp2f(c.x - M);
  float inv = 1.f / (w1 + w2);
  w1 *= inv; w2 *= inv;
  f16x8 o1 = *(const f16x8*)(op + i0 * 64 + c8 * 8);
  f16x8 o2 = *(const f16x8*)(op + i1 * 64 + c8 * 8);
  f16x8 o;
#pragma unroll
  for (int e = 0; e < 8; ++e)
    o[e] = (f16)(w1 * (float)o1[e] + w2 * (float)o2[e]);
  *(f16x8*)(attnout + ((size_t)b * 2048 + qrow) * 1024 + h * 64 + c8 * 8) = o;
}

extern "C" void kernel_launch(void* const* d_in, const int* in_sizes, int n_in,
                              void* d_out, int out_size, void* d_ws, size_t ws_size,
                              hipStream_t stream) {
  (void)in_sizes; (void)n_in; (void)out_size; (void)ws_size;
  const float* query = (const float*)d_in[0];
  const float* key   = (const float*)d_in[1];
  const float* value = (const float*)d_in[2];
  const float* wq = (const float*)d_in[3];
  const float* bq = (const float*)d_in[4];
  const float* wk = (const float*)d_in[5];
  const float* bk = (const float*)d_in[6];
  const float* wv = (const float*)d_in[7];
  const float* bv = (const float*)d_in[8];
  const float* wo = (const float*)d_in[9];
  const float* bo = (const float*)d_in[10];
  const float* cosT = (const float*)d_in[11];
  const float* sinT = (const float*)d_in[12];
  float* out = (float*)d_out;
  f16* ws = (f16*)d_ws;
  const size_t SEG = (size_t)4 * 1024 * 1024;
  f16* Xh = ws;                       // 3*SEG halves (query/key/value fp16)
  f16* Wh = ws + 3 * SEG;             // 4*1M halves (wq,wk,wv,wo fp16)
  f16* qh = ws + 16u * 1024 * 1024;   // SEG
  f16* kh = qh + SEG;                 // SEG
  f16* vt = kh + SEG;                 // SEG (total 56 MB)
  f16* attnout = ws;                  // aliases queryh (dead after projections)
  f16* op = ws + SEG;                 // aliases keyh+valueh (dead): 8M halves
  float2* mlb = (float2*)(ws + 12u * 1024 * 1024);  // aliases wqh (dead): 1MB

  convert_k<<<8192, 256, 0, stream>>>(query, key, value, wq, wk, wv, wo, ws);
  gemm_k<1><<<dim3(8, 32, 3), 256, 0, stream>>>(Xh, Wh, bq, bk, bv, cosT, sinT,
                                                qh, kh, vt, nullptr);
  flash_k<<<1024, 256, 0, stream>>>(qh, kh, vt, op, mlb);
  combine_k<<<2048, 256, 0, stream>>>(op, mlb, attnout);
  gemm_k<0><<<dim3(8, 32, 1), 256, 0, stream>>>(attnout, Wh + 3u * 1024 * 1024, bo,
                                                nullptr, nullptr, nullptr, nullptr,
                                                nullptr, nullptr, nullptr, out);
}

// Round 13
// 144.217 us; speedup vs baseline: 1.1818x; 1.0042x over previous
//
#include <hip/hip_runtime.h>
#include <hip/hip_fp16.h>

typedef _Float16 f16;
using f16x8 = __attribute__((ext_vector_type(8))) _Float16;
using h2 = __attribute__((ext_vector_type(2))) __fp16;   // cvt_pkrtz return type
using f32x4 = __attribute__((ext_vector_type(4))) float;
using f32x16 = __attribute__((ext_vector_type(16))) float;

#define LOG2E 1.4426950408889634f

__device__ __forceinline__ void gload16(const void* g, void* l) {
  __builtin_amdgcn_global_load_lds(
      (const __attribute__((address_space(1))) void*)g,
      (__attribute__((address_space(3))) void*)l, 16, 0, 0);
}

__device__ __forceinline__ float b32(h2 x) { return __builtin_bit_cast(float, x); }
__device__ __forceinline__ unsigned u32(h2 x) { return __builtin_bit_cast(unsigned, x); }

// ---------------- convert f32 -> fp16 ----------------
// ws layout (halves): [queryh 4M][keyh 4M][valueh 4M][wqh 1M][wkh 1M][wvh 1M][woh 1M]
__global__ __launch_bounds__(256) void convert_k(
    const float* __restrict__ q, const float* __restrict__ k, const float* __restrict__ v,
    const float* __restrict__ wq, const float* __restrict__ wk,
    const float* __restrict__ wv, const float* __restrict__ wo,
    f16* __restrict__ dst) {
  const size_t SEG = (size_t)4 * 1024 * 1024;
  size_t i = ((size_t)blockIdx.x * 256 + threadIdx.x) * 8;
  const float* src; size_t off;
  if (i < SEG)            { src = q;  off = i; }
  else if (i < 2 * SEG)   { src = k;  off = i - SEG; }
  else if (i < 3 * SEG)   { src = v;  off = i - 2 * SEG; }
  else {
    size_t wi = i - 3 * SEG;
    int s = (int)(wi >> 20);
    src = (s == 0) ? wq : (s == 1) ? wk : (s == 2) ? wv : wo;
    off = wi & ((1u << 20) - 1);
  }
  float4 a = *(const float4*)(src + off);
  float4 b = *(const float4*)(src + off + 4);
  f16x8 o;
  o[0] = (f16)a.x; o[1] = (f16)a.y; o[2] = (f16)a.z; o[3] = (f16)a.w;
  o[4] = (f16)b.x; o[5] = (f16)b.y; o[6] = (f16)b.z; o[7] = (f16)b.w;
  *(f16x8*)(dst + i) = o;
}

// ---------------- GEMM: C = A @ W^T (+bias), 128x128 tile, BK=32 ----------------
// 3-deep LDS pipeline with counted vmcnt(8): ~2 compute-phases of latency coverage.
// XCD-swizzled block mapping; LDS-staged wide-store epilogue for QKV path.
template <int QKV>
__global__ __launch_bounds__(256) void gemm_k(
    const f16* __restrict__ Abase, const f16* __restrict__ Wbase,
    const float* __restrict__ b0, const float* __restrict__ b1, const float* __restrict__ b2,
    const float* __restrict__ cosT, const float* __restrict__ sinT,
    f16* __restrict__ qh, f16* __restrict__ kh, f16* __restrict__ vt,
    float* __restrict__ outF) {
  __shared__ f16 sm[6][128 * 32];   // A bufs 0..2, B bufs 3..5 (48 KB); epilogue reuses 0..3
  int tid = threadIdx.x, wid = tid >> 6, lane = tid & 63;
  int z = QKV ? blockIdx.z : 0;
  const f16* A = Abase + (size_t)z * (4u * 1024 * 1024);
  const f16* W = Wbase + (size_t)z * (1024u * 1024);

  // T1: XCD-aware swizzle. 256 blocks/z, 8 XCDs; each XCD gets 4 m-panels x all 8 n-blocks.
  int lid = blockIdx.x + (blockIdx.y << 3);
  int xcd = lid & 7, q = lid >> 3;
  int m0 = (xcd * 4 + (q & 3)) * 128;
  int n0 = (q >> 2) * 128;
  int wr = wid >> 1, wc = wid & 1;
  f32x4 acc[4][4] = {};

  // staging addresses (kt-invariant): thread stages 16B of row (tid>>2), slot XOR-swizzled
  int srow = tid >> 2;
  int sslot = (tid & 3) ^ (srow & 3);
  const f16* asrc0 = A + (size_t)(m0 + srow) * 1024 + sslot * 8;
  const f16* asrc1 = A + (size_t)(m0 + 64 + srow) * 1024 + sslot * 8;
  const f16* bsrc0 = W + (size_t)(n0 + srow) * 1024 + sslot * 8;
  const f16* bsrc1 = W + (size_t)(n0 + 64 + srow) * 1024 + sslot * 8;

  // frag read offsets (halves, kt-invariant)
  int aoff[4], boff[4];
#pragma unroll
  for (int i = 0; i < 4; ++i) {
    int row = wr * 64 + i * 16 + (lane & 15);
    aoff[i] = row * 32 + (((lane >> 4) ^ (row & 3)) * 8);
    int col = wc * 64 + i * 16 + (lane & 15);
    boff[i] = col * 32 + (((lane >> 4) ^ (col & 3)) * 8);
  }

#define GSTAGE(KT, BUF)                                                        \
  do {                                                                         \
    int k0_ = (KT) * 32;                                                       \
    gload16(asrc0 + k0_, (void*)(&sm[BUF][0] + wid * 512));                    \
    gload16(asrc1 + k0_, (void*)(&sm[BUF][0] + 2048 + wid * 512));             \
    gload16(bsrc0 + k0_, (void*)(&sm[3 + (BUF)][0] + wid * 512));              \
    gload16(bsrc1 + k0_, (void*)(&sm[3 + (BUF)][0] + 2048 + wid * 512));       \
  } while (0)

  // prologue: stage K-steps 0,1 (8 loads in flight)
  GSTAGE(0, 0);
  GSTAGE(1, 1);

  for (int kt = 0; kt < 32; ++kt) {
    int cb = kt % 3;
    if (kt + 2 < 32) {
      GSTAGE(kt + 2, (kt + 2) % 3);
      asm volatile("s_waitcnt vmcnt(8)" ::: "memory");  // kt's 4 loads done
    } else if (kt + 1 < 32) {
      asm volatile("s_waitcnt vmcnt(4)" ::: "memory");
    } else {
      asm volatile("s_waitcnt vmcnt(0)" ::: "memory");
    }
    __builtin_amdgcn_s_barrier();          // all waves' tile-kt stages visible
    __builtin_amdgcn_sched_barrier(0);     // fence: no ds_read hoisting (rule #18)
    f16x8 af[4], bf[4];
#pragma unroll
    for (int i = 0; i < 4; ++i) {
      af[i] = *(const f16x8*)(&sm[cb][0] + aoff[i]);
      bf[i] = *(const f16x8*)(&sm[3 + cb][0] + boff[i]);
    }
#pragma unroll
    for (int i = 0; i < 4; ++i)
#pragma unroll
      for (int j = 0; j < 4; ++j)
        acc[i][j] = __builtin_amdgcn_mfma_f32_16x16x32_f16(af[i], bf[j], acc[i][j], 0, 0, 0);
    __builtin_amdgcn_s_barrier();          // protect this buf from stage(kt+3)
  }
#undef GSTAGE

  const float* bias = QKV ? (z == 0 ? b0 : (z == 1 ? b1 : b2)) : b0;

  if (QKV) {
    // ---- phase 1: compute bias/RoPE, stage f16 tile into LDS (chunk-XOR swizzled) ----
    f16* Ct = &sm[0][0];  // [128][128] f16 = 32KB
#pragma unroll
    for (int i = 0; i < 4; ++i) {
#pragma unroll
      for (int j = 0; j < 4; ++j) {
#pragma unroll
        for (int r = 0; r < 4; ++r) {
          int row_l = wr * 64 + i * 16 + ((lane >> 4) << 2) + r;
          int col_l = wc * 64 + j * 16 + (lane & 15);
          int gcol = n0 + col_l;
          float val = acc[i][j][r] + bias[gcol];
          if (z < 2) {
            int s = (m0 + row_l) & 2047;
            float pr = __shfl_xor(val, 1);
            int j2 = gcol >> 1;
            float c = cosT[s * 512 + j2], sn = sinT[s * 512 + j2];
            val = (lane & 1) ? (c * val + sn * pr) : (c * val - sn * pr);
            if (z == 0) val *= 0.125f * LOG2E;  // fold 1/sqrt(DK) and log2(e) into Q
          }
          Ct[row_l * 128 + (col_l ^ ((row_l & 7) << 3))] = (f16)val;
        }
      }
    }
    __syncthreads();
    // ---- phase 2: wide coalesced stores ----
    int bb = m0 >> 11, sbase = m0 & 2047;
    if (z < 2) {
      // qh/kh [bh][s][dk]: thread owns one half-row (64 dk of one head)
      int row = tid >> 1, halfsel = tid & 1;
      int h = (n0 >> 6) + halfsel;
      f16* dst = (z == 0 ? qh : kh) +
                 (((size_t)bb * 16 + h) * 2048 + sbase + row) * 64;
#pragma unroll
      for (int ch = 0; ch < 8; ++ch) {
        int c = halfsel * 64 + ch * 8;
        f16x8 v = *(const f16x8*)(Ct + row * 128 + (c ^ ((row & 7) << 3)));
        *(f16x8*)(dst + ch * 8) = v;
      }
    } else {
      // vt [bh][dk][s]: thread owns one column (dk) x 128 rows (s); 8 x 16B contiguous stores
      int c = tid & 127, halfsel = tid >> 7;
      int h = (n0 >> 6) + (c >> 6), dk = c & 63;
      f16* dst = vt + (((size_t)bb * 16 + h) * 64 + dk) * 2048 + sbase + halfsel * 64;
#pragma unroll
      for (int g = 0; g < 8; ++g) {
        f16x8 v;
#pragma unroll
        for (int e = 0; e < 8; ++e) {
          int r = halfsel * 64 + g * 8 + e;
          v[e] = Ct[r * 128 + (c ^ ((r & 7) << 3))];
        }
        *(f16x8*)(dst + g * 8) = v;
      }
    }
  } else {
    // out-projection: f32 output, lane-coalesced 4B stores (64B runs)
#pragma unroll
    for (int i = 0; i < 4; ++i) {
#pragma unroll
      for (int j = 0; j < 4; ++j) {
#pragma unroll
        for (int r = 0; r < 4; ++r) {
          int grow = m0 + wr * 64 + i * 16 + ((lane >> 4) << 2) + r;
          int gcol = n0 + wc * 64 + j * 16 + (lane & 15);
          outF[(size_t)grow * 1024 + gcol] = acc[i][j][r] + bias[gcol];
        }
      }
    }
  }
}

// ---------------- flash attention: 32x32 swapped, LDS-staged, split-K x2 ----------------
// Online softmax with defer-max (R8-proven numerics, shfl_xor exchanges).
// setprio around MFMA clusters (T5). XCD-chunked grid. Single-shfl pack (algebraic halving).
__global__ __launch_bounds__(256, 4) void flash_k(
    const f16* __restrict__ qh, const f16* __restrict__ kh, const f16* __restrict__ vt,
    f16* __restrict__ op, float2* __restrict__ mlbuf) {
  __shared__ f16 Ks[2][64 * 64];
  __shared__ f16 Vs[2][64 * 64];   // Vs[dk][key]
  int tid = threadIdx.x, wid = tid >> 6, lane = tid & 63;
  int l31 = lane & 31, hi = lane >> 5;
  // XCD-chunked decode: bid%8 keyed to (h,z) pair -> each XCD owns 8 pairs x 16 q-tiles.
  int bid = blockIdx.x;
  int xcd = bid & 7, t = bid >> 3;
  int qt = t & 15, phi = t >> 4;
  int p = phi * 8 + xcd;
  int h = p & 15, z = p >> 4;      // z = b*2 + ks
  int b = z >> 1, ks = z & 1;
  size_t bh = (size_t)b * 16 + h;
  const f16* qp = qh + bh * (2048 * 64);
  const f16* kp = kh + bh * (2048 * 64) + (size_t)ks * 1024 * 64;
  const f16* vp = vt + bh * (64 * 2048) + ks * 1024;
  int qrow = qt * 128 + wid * 32 + l31;

  // Q fragments: qf[kk][e] = Q[qrow][kk*16 + hi*8 + e]
  f16x8 qf[4];
#pragma unroll
  for (int kk = 0; kk < 4; ++kk)
    qf[kk] = *(const f16x8*)(qp + (size_t)qrow * 64 + kk * 16 + hi * 8);

  // staging: tile = 64 rows x 128B = 512 16B-slots; 2 issues per array per thread.
  int srowA = tid >> 3, srowB = srowA + 32;
  int schA = (tid & 7) ^ (srowA & 7);
  int schB = (tid & 7) ^ (srowB & 7);
  const f16* ksrcA = kp + (size_t)srowA * 64 + schA * 8;    // + kt*4096
  const f16* ksrcB = kp + (size_t)srowB * 64 + schB * 8;
  const f16* vsrcA = vp + (size_t)srowA * 2048 + schA * 8;  // + kt*64
  const f16* vsrcB = vp + (size_t)srowB * 2048 + schB * 8;

  // swizzled read byte-offsets (same formula serves K rows=key and V rows=dk)
  int offr[2][4];
#pragma unroll
  for (int kb = 0; kb < 2; ++kb)
#pragma unroll
    for (int kk = 0; kk < 4; ++kk) {
      int row = kb * 32 + l31;
      offr[kb][kk] = (row * 128 + kk * 32 + hi * 16) ^ ((row & 7) << 4);
    }

  float m_ = -1e30f, l_ = 0.f;
  f32x16 oacc[2] = {};

  // prologue: stage tile 0 into buf 0 (4 loads in flight)
  gload16(ksrcA, (char*)&Ks[0][0] + tid * 16);
  gload16(ksrcB, (char*)&Ks[0][0] + 4096 + tid * 16);
  gload16(vsrcA, (char*)&Vs[0][0] + tid * 16);
  gload16(vsrcB, (char*)&Vs[0][0] + 4096 + tid * 16);

  int cur = 0;
  for (int kt = 0; kt < 16; ++kt) {
    if (kt < 15) {  // issue next-tile loads; keep in flight across barriers
      gload16(ksrcA + (size_t)(kt + 1) * 4096, (char*)&Ks[cur ^ 1][0] + tid * 16);
      gload16(ksrcB + (size_t)(kt + 1) * 4096, (char*)&Ks[cur ^ 1][0] + 4096 + tid * 16);
      gload16(vsrcA + (size_t)(kt + 1) * 64, (char*)&Vs[cur ^ 1][0] + tid * 16);
      gload16(vsrcB + (size_t)(kt + 1) * 64, (char*)&Vs[cur ^ 1][0] + 4096 + tid * 16);
      asm volatile("s_waitcnt vmcnt(4)" ::: "memory");  // tile kt's 4 loads done
    } else {
      asm volatile("s_waitcnt vmcnt(0)" ::: "memory");
    }
    __builtin_amdgcn_s_barrier();          // all waves' tile-kt stages visible
    __builtin_amdgcn_sched_barrier(0);     // fence (rule #18)

    // QK^T (S^T: lane owns one q-row, 32 scores across regs + cross-half)
    const char* kbase = (const char*)&Ks[cur][0];
    f32x16 sacc[2] = {};
    __builtin_amdgcn_s_setprio(1);
#pragma unroll
    for (int kb = 0; kb < 2; ++kb)
#pragma unroll
      for (int kk = 0; kk < 4; ++kk) {
        f16x8 af = *(const f16x8*)(kbase + offr[kb][kk]);
        sacc[kb] = __builtin_amdgcn_mfma_f32_32x32x16_f16(af, qf[kk], sacc[kb], 0, 0, 0);
      }
    __builtin_amdgcn_s_setprio(0);

    // tree max over 32 local scores, then cross-half
    float t16[16];
#pragma unroll
    for (int i = 0; i < 16; ++i) t16[i] = fmaxf(sacc[0][i], sacc[1][i]);
#pragma unroll
    for (int s = 8; s; s >>= 1)
#pragma unroll
      for (int i = 0; i < s; ++i) t16[i] = fmaxf(t16[i], t16[i + s]);
    float pmax = fmaxf(t16[0], __shfl_xor(t16[0], 32));

    // defer-max (T13, THR=8): wave-uniform rescale skip
    if (!__all(pmax <= m_ + 8.0f)) {
      float mn = fmaxf(m_, pmax);
      float al = __builtin_amdgcn_exp2f(m_ - mn);
      m_ = mn;
      l_ *= al;
#pragma unroll
      for (int mb = 0; mb < 2; ++mb)
#pragma unroll
        for (int i = 0; i < 16; ++i) oacc[mb][i] *= al;
    }

    // P = 2^(s - m), tree sum
#pragma unroll
    for (int kb = 0; kb < 2; ++kb)
#pragma unroll
      for (int i = 0; i < 16; ++i)
        sacc[kb][i] = __builtin_amdgcn_exp2f(sacc[kb][i] - m_);
#pragma unroll
    for (int i = 0; i < 16; ++i) t16[i] = sacc[0][i] + sacc[1][i];
#pragma unroll
    for (int s = 8; s; s >>= 1)
#pragma unroll
      for (int i = 0; i < s; ++i) t16[i] += t16[i + s];
    l_ += t16[0] + __shfl_xor(t16[0], 32);

    // pack P^T fragments: pa[kk] slot (hi,e) = key 16kk + 8hi + e (fp16).
    // Single-shfl exchange: u = hi?X:Y ; s = shfl_xor(u,32) gives both half-swapped words
    // (bit-identical to the two-shfl form; saves 8 DS ops/tile).
    f16x8 pa[4];
#pragma unroll
    for (int kk = 0; kk < 4; ++kk) {
      int kb = kk >> 1, c8 = (kk & 1) * 8;
      float wA = b32(__builtin_amdgcn_cvt_pkrtz(sacc[kb][c8 + 0], sacc[kb][c8 + 1]));
      float wB = b32(__builtin_amdgcn_cvt_pkrtz(sacc[kb][c8 + 2], sacc[kb][c8 + 3]));
      float wC = b32(__builtin_amdgcn_cvt_pkrtz(sacc[kb][c8 + 4], sacc[kb][c8 + 5]));
      float wD = b32(__builtin_amdgcn_cvt_pkrtz(sacc[kb][c8 + 6], sacc[kb][c8 + 7]));
      float uAC = hi ? wA : wC;                 // {lo: wC, hi: wA}
      float uBD = hi ? wB : wD;
      float sAC = __shfl_xor(uAC, 32);          // {lo: wA[l+32], hi: wC[l-32]}
      float sBD = __shfl_xor(uBD, 32);
      float4 ff;
      ff.x = hi ? sAC : wA;                     // {lo: wA,       hi: wC[l-32]}
      ff.y = hi ? sBD : wB;
      ff.z = hi ? wC : sAC;                     // {lo: wA[l+32], hi: wC}
      ff.w = hi ? wD : sBD;
      pa[kk] = __builtin_bit_cast(f16x8, ff);
    }

    // PV: out^T += V^T x P^T
    const char* vbase = (const char*)&Vs[cur][0];
    __builtin_amdgcn_s_setprio(1);
#pragma unroll
    for (int kk = 0; kk < 4; ++kk)
#pragma unroll
      for (int mb = 0; mb < 2; ++mb) {
        f16x8 av = *(const f16x8*)(vbase + offr[mb][kk]);
        oacc[mb] = __builtin_amdgcn_mfma_f32_32x32x16_f16(av, pa[kk], oacc[mb], 0, 0, 0);
      }
    __builtin_amdgcn_s_setprio(0);

    __builtin_amdgcn_s_barrier();          // protect buf from next iteration's stage
    cur ^= 1;
  }

  // epilogue: normalized partial O + (m,l)
  float inv = 1.f / l_;
  f16* orow = op + (((size_t)z * 16 + h) * 2048 + qrow) * 64;
#pragma unroll
  for (int mb = 0; mb < 2; ++mb)
#pragma unroll
    for (int g = 0; g < 4; ++g) {
      uint2 st;
      st.x = u32(__builtin_amdgcn_cvt_pkrtz(oacc[mb][4 * g + 0] * inv, oacc[mb][4 * g + 1] * inv));
      st.y = u32(__builtin_amdgcn_cvt_pkrtz(oacc[mb][4 * g + 2] * inv, oacc[mb][4 * g + 3] * inv));
      *(uint2*)(orow + mb * 32 + g * 8 + hi * 4) = st;
    }
  if (hi == 0)
    mlbuf[((size_t)z * 16 + h) * 2048 + qrow] = make_float2(m_, l_);
}

// ---------------- combine the two split-K halves ----------------
__global__ __launch_bounds__(256) void combine_k(
    const f16* __restrict__ op, const float2* __restrict__ ml, f16* __restrict__ attnout) {
  int t = blockIdx.x * 256 + threadIdx.x;
  int row = t >> 3, c8 = t & 7;
  int b = row >> 15, h = (row >> 11) & 15, qrow = row & 2047;
  size_t i0 = ((size_t)(b * 2 + 0) * 16 + h) * 2048 + qrow;
  size_t i1 = ((size_t)(b * 2 + 1) * 16 + h) * 2048 + qrow;
  float2 a = ml[i0], c = ml[i1];
  float M = fmaxf(a.x, c.x);
  float w1 = a.y * __builtin_amdgcn_exp2f(a.x - M);
  float w2 = c.y * __builtin_amdgcn_exp2f(c.x - M);
  float inv = 1.f / (w1 + w2);
  w1 *= inv; w2 *= inv;
  f16x8 o1 = *(const f16x8*)(op + i0 * 64 + c8 * 8);
  f16x8 o2 = *(const f16x8*)(op + i1 * 64 + c8 * 8);
  f16x8 o;
#pragma unroll
  for (int e = 0; e < 8; ++e)
    o[e] = (f16)(w1 * (float)o1[e] + w2 * (float)o2[e]);
  *(f16x8*)(attnout + ((size_t)b * 2048 + qrow) * 1024 + h * 64 + c8 * 8) = o;
}

extern "C" void kernel_launch(void* const* d_in, const int* in_sizes, int n_in,
                              void* d_out, int out_size, void* d_ws, size_t ws_size,
                              hipStream_t stream) {
  (void)in_sizes; (void)n_in; (void)out_size; (void)ws_size;
  const float* query = (const float*)d_in[0];
  const float* key   = (const float*)d_in[1];
  const float* value = (const float*)d_in[2];
  const float* wq = (const float*)d_in[3];
  const float* bq = (const float*)d_in[4];
  const float* wk = (const float*)d_in[5];
  const float* bk = (const float*)d_in[6];
  const float* wv = (const float*)d_in[7];
  const float* bv = (const float*)d_in[8];
  const float* wo = (const float*)d_in[9];
  const float* bo = (const float*)d_in[10];
  const float* cosT = (const float*)d_in[11];
  const float* sinT = (const float*)d_in[12];
  float* out = (float*)d_out;
  f16* ws = (f16*)d_ws;
  const size_t SEG = (size_t)4 * 1024 * 1024;
  f16* Xh = ws;                       // 3*SEG halves (query/key/value fp16)
  f16* Wh = ws + 3 * SEG;             // 4*1M halves (wq,wk,wv,wo fp16)
  f16* qh = ws + 16u * 1024 * 1024;   // SEG
  f16* kh = qh + SEG;                 // SEG
  f16* vt = kh + SEG;                 // SEG (total 56 MB)
  f16* attnout = ws;                  // aliases queryh (dead after projections)
  f16* op = ws + SEG;                 // aliases keyh+valueh (dead): 8M halves
  float2* mlb = (float2*)(ws + 12u * 1024 * 1024);  // aliases wqh (dead): 1MB

  convert_k<<<8192, 256, 0, stream>>>(query, key, value, wq, wk, wv, wo, ws);
  gemm_k<1><<<dim3(8, 32, 3), 256, 0, stream>>>(Xh, Wh, bq, bk, bv, cosT, sinT,
                                                qh, kh, vt, nullptr);
  flash_k<<<1024, 256, 0, stream>>>(qh, kh, vt, op, mlb);
  combine_k<<<2048, 256, 0, stream>>>(op, mlb, attnout);
  gemm_k<0><<<dim3(8, 32, 1), 256, 0, stream>>>(attnout, Wh + 3u * 1024 * 1024, bo,
                                                nullptr, nullptr, nullptr, nullptr,
                                                nullptr, nullptr, nullptr, out);
}

// Round 14
// 141.790 us; speedup vs baseline: 1.2020x; 1.0171x over previous
//
#include <hip/hip_runtime.h>
#include <hip/hip_fp16.h>

typedef _Float16 f16;
using f16x8 = __attribute__((ext_vector_type(8))) _Float16;
using h2 = __attribute__((ext_vector_type(2))) __fp16;   // cvt_pkrtz return type
using f32x4 = __attribute__((ext_vector_type(4))) float;
using f32x16 = __attribute__((ext_vector_type(16))) float;

#define LOG2E 1.4426950408889634f

__device__ __forceinline__ void gload16(const void* g, void* l) {
  __builtin_amdgcn_global_load_lds(
      (const __attribute__((address_space(1))) void*)g,
      (__attribute__((address_space(3))) void*)l, 16, 0, 0);
}

__device__ __forceinline__ float b32(h2 x) { return __builtin_bit_cast(float, x); }
__device__ __forceinline__ unsigned u32(h2 x) { return __builtin_bit_cast(unsigned, x); }

// ---------------- convert f32 -> fp16 ----------------
// ws layout (halves): [queryh 4M][keyh 4M][valueh 4M][wqh 1M][wkh 1M][wvh 1M][woh 1M]
__global__ __launch_bounds__(256) void convert_k(
    const float* __restrict__ q, const float* __restrict__ k, const float* __restrict__ v,
    const float* __restrict__ wq, const float* __restrict__ wk,
    const float* __restrict__ wv, const float* __restrict__ wo,
    f16* __restrict__ dst) {
  const size_t SEG = (size_t)4 * 1024 * 1024;
  size_t i = ((size_t)blockIdx.x * 256 + threadIdx.x) * 8;
  const float* src; size_t off;
  if (i < SEG)            { src = q;  off = i; }
  else if (i < 2 * SEG)   { src = k;  off = i - SEG; }
  else if (i < 3 * SEG)   { src = v;  off = i - 2 * SEG; }
  else {
    size_t wi = i - 3 * SEG;
    int s = (int)(wi >> 20);
    src = (s == 0) ? wq : (s == 1) ? wk : (s == 2) ? wv : wo;
    off = wi & ((1u << 20) - 1);
  }
  float4 a = *(const float4*)(src + off);
  float4 b = *(const float4*)(src + off + 4);
  f16x8 o;
  o[0] = (f16)a.x; o[1] = (f16)a.y; o[2] = (f16)a.z; o[3] = (f16)a.w;
  o[4] = (f16)b.x; o[5] = (f16)b.y; o[6] = (f16)b.z; o[7] = (f16)b.w;
  *(f16x8*)(dst + i) = o;
}

// ---------------- GEMM: C = A @ W^T (+bias), 128x128 tile, BK=32 ----------------
// 3-deep LDS pipeline with counted vmcnt(8): ~2 compute-phases of latency coverage.
// XCD-swizzled block mapping; LDS-staged wide-store epilogue for QKV path.
template <int QKV>
__global__ __launch_bounds__(256) void gemm_k(
    const f16* __restrict__ Abase, const f16* __restrict__ Wbase,
    const float* __restrict__ b0, const float* __restrict__ b1, const float* __restrict__ b2,
    const float* __restrict__ cosT, const float* __restrict__ sinT,
    f16* __restrict__ qh, f16* __restrict__ kh, f16* __restrict__ vt,
    float* __restrict__ outF) {
  __shared__ f16 sm[6][128 * 32];   // A bufs 0..2, B bufs 3..5 (48 KB); epilogue reuses 0..3
  int tid = threadIdx.x, wid = tid >> 6, lane = tid & 63;
  int z = QKV ? blockIdx.z : 0;
  const f16* A = Abase + (size_t)z * (4u * 1024 * 1024);
  const f16* W = Wbase + (size_t)z * (1024u * 1024);

  // T1: XCD-aware swizzle. 256 blocks/z, 8 XCDs; each XCD gets 4 m-panels x all 8 n-blocks.
  int lid = blockIdx.x + (blockIdx.y << 3);
  int xcd = lid & 7, q = lid >> 3;
  int m0 = (xcd * 4 + (q & 3)) * 128;
  int n0 = (q >> 2) * 128;
  int wr = wid >> 1, wc = wid & 1;
  f32x4 acc[4][4] = {};

  // staging addresses (kt-invariant): thread stages 16B of row (tid>>2), slot XOR-swizzled
  int srow = tid >> 2;
  int sslot = (tid & 3) ^ (srow & 3);
  const f16* asrc0 = A + (size_t)(m0 + srow) * 1024 + sslot * 8;
  const f16* asrc1 = A + (size_t)(m0 + 64 + srow) * 1024 + sslot * 8;
  const f16* bsrc0 = W + (size_t)(n0 + srow) * 1024 + sslot * 8;
  const f16* bsrc1 = W + (size_t)(n0 + 64 + srow) * 1024 + sslot * 8;

  // frag read offsets (halves, kt-invariant)
  int aoff[4], boff[4];
#pragma unroll
  for (int i = 0; i < 4; ++i) {
    int row = wr * 64 + i * 16 + (lane & 15);
    aoff[i] = row * 32 + (((lane >> 4) ^ (row & 3)) * 8);
    int col = wc * 64 + i * 16 + (lane & 15);
    boff[i] = col * 32 + (((lane >> 4) ^ (col & 3)) * 8);
  }

#define GSTAGE(KT, BUF)                                                        \
  do {                                                                         \
    int k0_ = (KT) * 32;                                                       \
    gload16(asrc0 + k0_, (void*)(&sm[BUF][0] + wid * 512));                    \
    gload16(asrc1 + k0_, (void*)(&sm[BUF][0] + 2048 + wid * 512));             \
    gload16(bsrc0 + k0_, (void*)(&sm[3 + (BUF)][0] + wid * 512));              \
    gload16(bsrc1 + k0_, (void*)(&sm[3 + (BUF)][0] + 2048 + wid * 512));       \
  } while (0)

  // prologue: stage K-steps 0,1 (8 loads in flight)
  GSTAGE(0, 0);
  GSTAGE(1, 1);

  for (int kt = 0; kt < 32; ++kt) {
    int cb = kt % 3;
    if (kt + 2 < 32) {
      GSTAGE(kt + 2, (kt + 2) % 3);
      asm volatile("s_waitcnt vmcnt(8)" ::: "memory");  // kt's 4 loads done
    } else if (kt + 1 < 32) {
      asm volatile("s_waitcnt vmcnt(4)" ::: "memory");
    } else {
      asm volatile("s_waitcnt vmcnt(0)" ::: "memory");
    }
    __builtin_amdgcn_s_barrier();          // all waves' tile-kt stages visible
    __builtin_amdgcn_sched_barrier(0);     // fence: no ds_read hoisting (rule #18)
    f16x8 af[4], bf[4];
#pragma unroll
    for (int i = 0; i < 4; ++i) {
      af[i] = *(const f16x8*)(&sm[cb][0] + aoff[i]);
      bf[i] = *(const f16x8*)(&sm[3 + cb][0] + boff[i]);
    }
#pragma unroll
    for (int i = 0; i < 4; ++i)
#pragma unroll
      for (int j = 0; j < 4; ++j)
        acc[i][j] = __builtin_amdgcn_mfma_f32_16x16x32_f16(af[i], bf[j], acc[i][j], 0, 0, 0);
    __builtin_amdgcn_s_barrier();          // protect this buf from stage(kt+3)
  }
#undef GSTAGE

  const float* bias = QKV ? (z == 0 ? b0 : (z == 1 ? b1 : b2)) : b0;

  if (QKV) {
    // ---- phase 1: compute bias/RoPE, stage f16 tile into LDS (chunk-XOR swizzled) ----
    f16* Ct = &sm[0][0];  // [128][128] f16 = 32KB
#pragma unroll
    for (int i = 0; i < 4; ++i) {
#pragma unroll
      for (int j = 0; j < 4; ++j) {
#pragma unroll
        for (int r = 0; r < 4; ++r) {
          int row_l = wr * 64 + i * 16 + ((lane >> 4) << 2) + r;
          int col_l = wc * 64 + j * 16 + (lane & 15);
          int gcol = n0 + col_l;
          float val = acc[i][j][r] + bias[gcol];
          if (z < 2) {
            int s = (m0 + row_l) & 2047;
            float pr = __shfl_xor(val, 1);
            int j2 = gcol >> 1;
            float c = cosT[s * 512 + j2], sn = sinT[s * 512 + j2];
            val = (lane & 1) ? (c * val + sn * pr) : (c * val - sn * pr);
            if (z == 0) val *= 0.125f * LOG2E;  // fold 1/sqrt(DK) and log2(e) into Q
          }
          Ct[row_l * 128 + (col_l ^ ((row_l & 7) << 3))] = (f16)val;
        }
      }
    }
    __syncthreads();
    // ---- phase 2: wide coalesced stores ----
    int bb = m0 >> 11, sbase = m0 & 2047;
    if (z < 2) {
      // qh/kh [bh][s][dk]: thread owns one half-row (64 dk of one head)
      int row = tid >> 1, halfsel = tid & 1;
      int h = (n0 >> 6) + halfsel;
      f16* dst = (z == 0 ? qh : kh) +
                 (((size_t)bb * 16 + h) * 2048 + sbase + row) * 64;
#pragma unroll
      for (int ch = 0; ch < 8; ++ch) {
        int c = halfsel * 64 + ch * 8;
        f16x8 v = *(const f16x8*)(Ct + row * 128 + (c ^ ((row & 7) << 3)));
        *(f16x8*)(dst + ch * 8) = v;
      }
    } else {
      // vt [bh][dk][s]: thread owns one column (dk) x 128 rows (s); 8 x 16B contiguous stores
      int c = tid & 127, halfsel = tid >> 7;
      int h = (n0 >> 6) + (c >> 6), dk = c & 63;
      f16* dst = vt + (((size_t)bb * 16 + h) * 64 + dk) * 2048 + sbase + halfsel * 64;
#pragma unroll
      for (int g = 0; g < 8; ++g) {
        f16x8 v;
#pragma unroll
        for (int e = 0; e < 8; ++e) {
          int r = halfsel * 64 + g * 8 + e;
          v[e] = Ct[r * 128 + (c ^ ((r & 7) << 3))];
        }
        *(f16x8*)(dst + g * 8) = v;
      }
    }
  } else {
    // out-projection: f32 output, lane-coalesced 4B stores (64B runs)
#pragma unroll
    for (int i = 0; i < 4; ++i) {
#pragma unroll
      for (int j = 0; j < 4; ++j) {
#pragma unroll
        for (int r = 0; r < 4; ++r) {
          int grow = m0 + wr * 64 + i * 16 + ((lane >> 4) << 2) + r;
          int gcol = n0 + wc * 64 + j * 16 + (lane & 15);
          outF[(size_t)grow * 1024 + gcol] = acc[i][j][r] + bias[gcol];
        }
      }
    }
  }
}

// ---------------- flash attention: 32x32 swapped, LDS-staged, split-K x2 ----------------
// 8-wave blocks (QBLK=256): 2 blocks/CU x 8 waves = 16 waves/CU (50% occupancy, the
// VGPR-imposed ceiling). Per-wave structure identical to the 4-wave version.
__global__ __launch_bounds__(512, 4) void flash_k(
    const f16* __restrict__ qh, const f16* __restrict__ kh, const f16* __restrict__ vt,
    f16* __restrict__ op, float2* __restrict__ mlbuf) {
  __shared__ f16 Ks[2][64 * 64];
  __shared__ f16 Vs[2][64 * 64];   // Vs[dk][key]
  int tid = threadIdx.x, wid = tid >> 6, lane = tid & 63;
  int l31 = lane & 31, hi = lane >> 5;
  // XCD-chunked decode: bid%8 keyed to (h,z) pair -> each XCD owns 8 pairs x 8 q-tiles.
  int bid = blockIdx.x;
  int xcd = bid & 7, t = bid >> 3;     // t in [0,64)
  int qt = t & 7, phi = t >> 3;        // qt in [0,8), phi in [0,8)
  int p = phi * 8 + xcd;               // (h,z) pair in [0,64)
  int h = p & 15, z = p >> 4;          // z = b*2 + ks
  int b = z >> 1, ks = z & 1;
  size_t bh = (size_t)b * 16 + h;
  const f16* qp = qh + bh * (2048 * 64);
  const f16* kp = kh + bh * (2048 * 64) + (size_t)ks * 1024 * 64;
  const f16* vp = vt + bh * (64 * 2048) + ks * 1024;
  int qrow = qt * 256 + wid * 32 + l31;

  // Q fragments: qf[kk][e] = Q[qrow][kk*16 + hi*8 + e]
  f16x8 qf[4];
#pragma unroll
  for (int kk = 0; kk < 4; ++kk)
    qf[kk] = *(const f16x8*)(qp + (size_t)qrow * 64 + kk * 16 + hi * 8);

  // staging: tile = 64 rows x 128B = 512 16B-slots; 1 slot per thread per array.
  // physical slot (row, c) holds logical chunk c ^ (row&7)
  int srow = tid >> 3;
  int sch = (tid & 7) ^ (srow & 7);
  const f16* ksrc = kp + (size_t)srow * 64 + sch * 8;    // + kt*4096
  const f16* vsrc = vp + (size_t)srow * 2048 + sch * 8;  // + kt*64

  // swizzled read byte-offsets (same formula serves K rows=key and V rows=dk)
  int offr[2][4];
#pragma unroll
  for (int kb = 0; kb < 2; ++kb)
#pragma unroll
    for (int kk = 0; kk < 4; ++kk) {
      int row = kb * 32 + l31;
      offr[kb][kk] = (row * 128 + kk * 32 + hi * 16) ^ ((row & 7) << 4);
    }

  float m_ = -1e30f, l_ = 0.f;
  f32x16 oacc[2] = {};

  // prologue: stage tile 0 into buf 0 (2 loads in flight)
  gload16(ksrc, (char*)&Ks[0][0] + tid * 16);
  gload16(vsrc, (char*)&Vs[0][0] + tid * 16);

  int cur = 0;
  for (int kt = 0; kt < 16; ++kt) {
    if (kt < 15) {  // issue next-tile loads; keep in flight across barriers
      gload16(ksrc + (size_t)(kt + 1) * 4096, (char*)&Ks[cur ^ 1][0] + tid * 16);
      gload16(vsrc + (size_t)(kt + 1) * 64, (char*)&Vs[cur ^ 1][0] + tid * 16);
      asm volatile("s_waitcnt vmcnt(2)" ::: "memory");  // tile kt's 2 loads done
    } else {
      asm volatile("s_waitcnt vmcnt(0)" ::: "memory");
    }
    __builtin_amdgcn_s_barrier();          // all waves' tile-kt stages visible
    __builtin_amdgcn_sched_barrier(0);     // fence (rule #18)

    // QK^T (S^T: lane owns one q-row, 32 scores across regs + cross-half)
    const char* kbase = (const char*)&Ks[cur][0];
    f32x16 sacc[2] = {};
    __builtin_amdgcn_s_setprio(1);
#pragma unroll
    for (int kb = 0; kb < 2; ++kb)
#pragma unroll
      for (int kk = 0; kk < 4; ++kk) {
        f16x8 af = *(const f16x8*)(kbase + offr[kb][kk]);
        sacc[kb] = __builtin_amdgcn_mfma_f32_32x32x16_f16(af, qf[kk], sacc[kb], 0, 0, 0);
      }
    __builtin_amdgcn_s_setprio(0);

    // tree max over 32 local scores, then cross-half
    float t16[16];
#pragma unroll
    for (int i = 0; i < 16; ++i) t16[i] = fmaxf(sacc[0][i], sacc[1][i]);
#pragma unroll
    for (int s = 8; s; s >>= 1)
#pragma unroll
      for (int i = 0; i < s; ++i) t16[i] = fmaxf(t16[i], t16[i + s]);
    float pmax = fmaxf(t16[0], __shfl_xor(t16[0], 32));

    // defer-max (T13, THR=8): wave-uniform rescale skip
    if (!__all(pmax <= m_ + 8.0f)) {
      float mn = fmaxf(m_, pmax);
      float al = __builtin_amdgcn_exp2f(m_ - mn);
      m_ = mn;
      l_ *= al;
#pragma unroll
      for (int mb = 0; mb < 2; ++mb)
#pragma unroll
        for (int i = 0; i < 16; ++i) oacc[mb][i] *= al;
    }

    // P = 2^(s - m), tree sum
#pragma unroll
    for (int kb = 0; kb < 2; ++kb)
#pragma unroll
      for (int i = 0; i < 16; ++i)
        sacc[kb][i] = __builtin_amdgcn_exp2f(sacc[kb][i] - m_);
#pragma unroll
    for (int i = 0; i < 16; ++i) t16[i] = sacc[0][i] + sacc[1][i];
#pragma unroll
    for (int s = 8; s; s >>= 1)
#pragma unroll
      for (int i = 0; i < s; ++i) t16[i] += t16[i + s];
    l_ += t16[0] + __shfl_xor(t16[0], 32);

    // pack P^T fragments: pa[kk] slot (hi,e) = key 16kk + 8hi + e (fp16).
    // Single-shfl exchange: u = hi?X:Y ; s = shfl_xor(u,32) gives both half-swapped words
    f16x8 pa[4];
#pragma unroll
    for (int kk = 0; kk < 4; ++kk) {
      int kb = kk >> 1, c8 = (kk & 1) * 8;
      float wA = b32(__builtin_amdgcn_cvt_pkrtz(sacc[kb][c8 + 0], sacc[kb][c8 + 1]));
      float wB = b32(__builtin_amdgcn_cvt_pkrtz(sacc[kb][c8 + 2], sacc[kb][c8 + 3]));
      float wC = b32(__builtin_amdgcn_cvt_pkrtz(sacc[kb][c8 + 4], sacc[kb][c8 + 5]));
      float wD = b32(__builtin_amdgcn_cvt_pkrtz(sacc[kb][c8 + 6], sacc[kb][c8 + 7]));
      float uAC = hi ? wA : wC;                 // {lo: wC, hi: wA}
      float uBD = hi ? wB : wD;
      float sAC = __shfl_xor(uAC, 32);          // {lo: wA[l+32], hi: wC[l-32]}
      float sBD = __shfl_xor(uBD, 32);
      float4 ff;
      ff.x = hi ? sAC : wA;                     // {lo: wA,       hi: wC[l-32]}
      ff.y = hi ? sBD : wB;
      ff.z = hi ? wC : sAC;                     // {lo: wA[l+32], hi: wC}
      ff.w = hi ? wD : sBD;
      pa[kk] = __builtin_bit_cast(f16x8, ff);
    }

    // PV: out^T += V^T x P^T
    const char* vbase = (const char*)&Vs[cur][0];
    __builtin_amdgcn_s_setprio(1);
#pragma unroll
    for (int kk = 0; kk < 4; ++kk)
#pragma unroll
      for (int mb = 0; mb < 2; ++mb) {
        f16x8 av = *(const f16x8*)(vbase + offr[mb][kk]);
        oacc[mb] = __builtin_amdgcn_mfma_f32_32x32x16_f16(av, pa[kk], oacc[mb], 0, 0, 0);
      }
    __builtin_amdgcn_s_setprio(0);

    __builtin_amdgcn_s_barrier();          // protect buf from next iteration's stage
    cur ^= 1;
  }

  // epilogue: normalized partial O + (m,l)
  float inv = 1.f / l_;
  f16* orow = op + (((size_t)z * 16 + h) * 2048 + qrow) * 64;
#pragma unroll
  for (int mb = 0; mb < 2; ++mb)
#pragma unroll
    for (int g = 0; g < 4; ++g) {
      uint2 st;
      st.x = u32(__builtin_amdgcn_cvt_pkrtz(oacc[mb][4 * g + 0] * inv, oacc[mb][4 * g + 1] * inv));
      st.y = u32(__builtin_amdgcn_cvt_pkrtz(oacc[mb][4 * g + 2] * inv, oacc[mb][4 * g + 3] * inv));
      *(uint2*)(orow + mb * 32 + g * 8 + hi * 4) = st;
    }
  if (hi == 0)
    mlbuf[((size_t)z * 16 + h) * 2048 + qrow] = make_float2(m_, l_);
}

// ---------------- combine the two split-K halves ----------------
__global__ __launch_bounds__(256) void combine_k(
    const f16* __restrict__ op, const float2* __restrict__ ml, f16* __restrict__ attnout) {
  int t = blockIdx.x * 256 + threadIdx.x;
  int row = t >> 3, c8 = t & 7;
  int b = row >> 15, h = (row >> 11) & 15, qrow = row & 2047;
  size_t i0 = ((size_t)(b * 2 + 0) * 16 + h) * 2048 + qrow;
  size_t i1 = ((size_t)(b * 2 + 1) * 16 + h) * 2048 + qrow;
  float2 a = ml[i0], c = ml[i1];
  float M = fmaxf(a.x, c.x);
  float w1 = a.y * __builtin_amdgcn_exp2f(a.x - M);
  float w2 = c.y * __builtin_amdgcn_exp2f(c.x - M);
  float inv = 1.f / (w1 + w2);
  w1 *= inv; w2 *= inv;
  f16x8 o1 = *(const f16x8*)(op + i0 * 64 + c8 * 8);
  f16x8 o2 = *(const f16x8*)(op + i1 * 64 + c8 * 8);
  f16x8 o;
#pragma unroll
  for (int e = 0; e < 8; ++e)
    o[e] = (f16)(w1 * (float)o1[e] + w2 * (float)o2[e]);
  *(f16x8*)(attnout + ((size_t)b * 2048 + qrow) * 1024 + h * 64 + c8 * 8) = o;
}

extern "C" void kernel_launch(void* const* d_in, const int* in_sizes, int n_in,
                              void* d_out, int out_size, void* d_ws, size_t ws_size,
                              hipStream_t stream) {
  (void)in_sizes; (void)n_in; (void)out_size; (void)ws_size;
  const float* query = (const float*)d_in[0];
  const float* key   = (const float*)d_in[1];
  const float* value = (const float*)d_in[2];
  const float* wq = (const float*)d_in[3];
  const float* bq = (const float*)d_in[4];
  const float* wk = (const float*)d_in[5];
  const float* bk = (const float*)d_in[6];
  const float* wv = (const float*)d_in[7];
  const float* bv = (const float*)d_in[8];
  const float* wo = (const float*)d_in[9];
  const float* bo = (const float*)d_in[10];
  const float* cosT = (const float*)d_in[11];
  const float* sinT = (const float*)d_in[12];
  float* out = (float*)d_out;
  f16* ws = (f16*)d_ws;
  const size_t SEG = (size_t)4 * 1024 * 1024;
  f16* Xh = ws;                       // 3*SEG halves (query/key/value fp16)
  f16* Wh = ws + 3 * SEG;             // 4*1M halves (wq,wk,wv,wo fp16)
  f16* qh = ws + 16u * 1024 * 1024;   // SEG
  f16* kh = qh + SEG;                 // SEG
  f16* vt = kh + SEG;                 // SEG (total 56 MB)
  f16* attnout = ws;                  // aliases queryh (dead after projections)
  f16* op = ws + SEG;                 // aliases keyh+valueh (dead): 8M halves
  float2* mlb = (float2*)(ws + 12u * 1024 * 1024);  // aliases wqh (dead): 1MB

  convert_k<<<8192, 256, 0, stream>>>(query, key, value, wq, wk, wv, wo, ws);
  gemm_k<1><<<dim3(8, 32, 3), 256, 0, stream>>>(Xh, Wh, bq, bk, bv, cosT, sinT,
                                                qh, kh, vt, nullptr);
  flash_k<<<512, 512, 0, stream>>>(qh, kh, vt, op, mlb);
  combine_k<<<2048, 256, 0, stream>>>(op, mlb, attnout);
  gemm_k<0><<<dim3(8, 32, 1), 256, 0, stream>>>(attnout, Wh + 3u * 1024 * 1024, bo,
                                                nullptr, nullptr, nullptr, nullptr,
                                                nullptr, nullptr, nullptr, out);
}